// Round 5
// baseline (383.275 us; speedup 1.0000x reference)
//
#include <hip/hip_runtime.h>
#include <hip/hip_cooperative_groups.h>

namespace cg = cooperative_groups;

#define N_ROWS 65536
#define N_COLS 256
#define NCLASS 10
#define XP 66176            // Xst col pitch: 65536 + 10*64 pad
#define SPL 16              // K-splits per (class,tile)
#define MSZ 65536           // 256*256 elements per matrix
#define BE_GRID 240         // backend cooperative grid (<=256 CUs -> co-residency safe)

typedef __attribute__((ext_vector_type(8))) short bf16x8;
typedef __attribute__((ext_vector_type(4))) float f32x4;

// meta layout (ints): [0..10] off_pad, [16..26] offsets (unpadded), [32..41] counts
// slab layout (bf16): s*11*MSZ + m*MSZ for s in {0:E, 1:G=E^2, 2:H=E^3, 3:K=E^4}
// small region (1024B): [0..63] cvals, [64..767] traces, [960] done-counter (fallback)

static __device__ __forceinline__ unsigned short f2bf(float f) {
    unsigned int u = __float_as_uint(f);
    unsigned int r = (u + 0x7FFFu + ((u >> 16) & 1u)) >> 16;   // RTN-even
    return (unsigned short)r;
}
static __device__ __forceinline__ float bf2f(unsigned short s) {
    return __uint_as_float(((unsigned int)s) << 16);
}
static __device__ __forceinline__ void unpack8(const unsigned short* p, float* f) {
    uint4 u = *(const uint4*)p;
    f[0] = __uint_as_float(u.x << 16); f[1] = __uint_as_float(u.x & 0xffff0000u);
    f[2] = __uint_as_float(u.y << 16); f[3] = __uint_as_float(u.y & 0xffff0000u);
    f[4] = __uint_as_float(u.z << 16); f[5] = __uint_as_float(u.z & 0xffff0000u);
    f[6] = __uint_as_float(u.w << 16); f[7] = __uint_as_float(u.w & 0xffff0000u);
}
static __device__ __forceinline__ float scal_of(int b, const int* meta) {
    if (b < NCLASS) return (float)N_COLS / (((float)meta[32 + b] + 1e-8f) * 0.01f);
    return (float)N_COLS / ((float)N_ROWS * 0.01f);
}

// ---------------- Phase A: per-block class histogram (256 blocks) ----------------
__global__ __launch_bounds__(256) void blkhist_kernel(const int* __restrict__ Y,
                                                      int* __restrict__ blk_cnt) {
    __shared__ int h[NCLASS];
    int b = blockIdx.x, t = threadIdx.x;
    if (t < NCLASS) h[t] = 0;
    __syncthreads();
    atomicAdd(&h[Y[b * 256 + t]], 1);
    __syncthreads();
    if (t < NCLASS) blk_cnt[b * NCLASS + t] = h[t];
}

// ---------------- Phase B: scan (wave-per-class shuffle scans, 1 block) ----------------
// Also zeroes the small region (cvals/traces/ctr) so no separate memset dispatch.
__global__ __launch_bounds__(1024) void scan_kernel(const int* __restrict__ blk_cnt,
                                                    int* __restrict__ meta,
                                                    int* __restrict__ blk_base,
                                                    unsigned int* __restrict__ smallz) {
    int t = threadIdx.x;
    if (t < 256) smallz[t] = 0u;          // zero cvals+traces+ctr (1024 B)
    int w = t >> 6, l = t & 63;
    __shared__ int tots[16];
    __shared__ int soff_s[16];
    int s0 = 0, s1 = 0, s2 = 0, s3 = 0;
    if (w < NCLASS) {
        s0 = blk_cnt[(l      ) * NCLASS + w];
        s1 = blk_cnt[(l +  64) * NCLASS + w];
        s2 = blk_cnt[(l + 128) * NCLASS + w];
        s3 = blk_cnt[(l + 192) * NCLASS + w];
    }
    int x0 = s0, x1 = s1, x2 = s2, x3 = s3;
    for (int d = 1; d < 64; d <<= 1) {
        int y0 = __shfl_up(x0, d, 64), y1 = __shfl_up(x1, d, 64);
        int y2 = __shfl_up(x2, d, 64), y3 = __shfl_up(x3, d, 64);
        if (l >= d) { x0 += y0; x1 += y1; x2 += y2; x3 += y3; }
    }
    int T0 = __shfl(x0, 63, 64), T1 = __shfl(x1, 63, 64);
    int T2 = __shfl(x2, 63, 64), T3 = __shfl(x3, 63, 64);
    if (w < NCLASS && l == 63) tots[w] = T0 + T1 + T2 + T3;
    __syncthreads();
    if (t == 0) {
        int off = 0, offp = 0;
        for (int c = 0; c < NCLASS; ++c) {
            soff_s[c] = off;
            meta[16 + c] = off;
            meta[c] = offp;
            meta[32 + c] = tots[c];
            off += tots[c];
            offp += (tots[c] + 63) & ~63;
        }
        meta[16 + NCLASS] = off;
        meta[NCLASS] = offp;
    }
    __syncthreads();
    if (w < NCLASS) {
        int base = soff_s[w];
        blk_base[(l      ) * NCLASS + w] = base + x0 - s0;
        blk_base[(l +  64) * NCLASS + w] = base + T0 + x1 - s1;
        blk_base[(l + 128) * NCLASS + w] = base + T0 + T1 + x2 - s2;
        blk_base[(l + 192) * NCLASS + w] = base + T0 + T1 + T2 + x3 - s3;
    }
}

// ---------------- Phase C: build sorted order (256 blocks) ----------------
__global__ __launch_bounds__(256) void order_kernel(const int* __restrict__ Y,
                                                    const int* __restrict__ blk_base,
                                                    int* __restrict__ order) {
    __shared__ int lcur[NCLASS];
    int b = blockIdx.x, t = threadIdx.x;
    if (t < NCLASS) lcur[t] = 0;
    __syncthreads();
    int i = b * 256 + t;
    int y = Y[i];
    int pos = blk_base[b * NCLASS + y] + atomicAdd(&lcur[y], 1);
    order[pos] = i;
}

// ---------------- gather + fp32->bf16 + transpose (rotation-swizzled LDS) ----------------
// 512 threads: 8 waves/block, 4 blocks/CU (LDS 32KB) -> 32 waves/CU resident.
__global__ __launch_bounds__(512) void gather_kernel(const float* __restrict__ X,
                                                     const int* __restrict__ order,
                                                     const int* __restrict__ meta,
                                                     unsigned short* __restrict__ Xst) {
    __shared__ unsigned int sT32[256 * 32];   // 32 KB
    int p0 = blockIdx.x * 64;
    if (p0 >= meta[NCLASS]) return;
    int cls = 0;
    while (p0 >= meta[cls + 1]) ++cls;       // 64-tiles never straddle classes
    int lp0 = p0 - meta[cls];
    int cnt = meta[32 + cls];
    int obase = meta[16 + cls];

    int t = threadIdx.x;
    int w = t >> 6, l = t & 63;

    #pragma unroll
    for (int rp = 0; rp < 4; ++rp) {
        int p2 = w * 4 + rp;                  // 0..31 (pos pair index)
        int lpa = lp0 + p2 * 2;
        int lpb = lpa + 1;
        int ra = (lpa < cnt) ? order[obase + lpa] : -1;   // wave-uniform
        int rb = (lpb < cnt) ? order[obase + lpb] : -1;
        float4 va = make_float4(0.f, 0.f, 0.f, 0.f);
        float4 vb = make_float4(0.f, 0.f, 0.f, 0.f);
        if (ra >= 0) va = *(const float4*)(X + (size_t)ra * N_COLS + l * 4);
        if (rb >= 0) vb = *(const float4*)(X + (size_t)rb * N_COLS + l * 4);
        unsigned int d0 = (unsigned)f2bf(va.x) | ((unsigned)f2bf(vb.x) << 16);
        unsigned int d1 = (unsigned)f2bf(va.y) | ((unsigned)f2bf(vb.y) << 16);
        unsigned int d2 = (unsigned)f2bf(va.z) | ((unsigned)f2bf(vb.z) << 16);
        unsigned int d3 = (unsigned)f2bf(va.w) | ((unsigned)f2bf(vb.w) << 16);
        int c0 = l * 4;
        sT32[(c0 + 0) * 32 + ((p2 + l + 0) & 31)] = d0;
        sT32[(c0 + 1) * 32 + ((p2 + l + 1) & 31)] = d1;
        sT32[(c0 + 2) * 32 + ((p2 + l + 2) & 31)] = d2;
        sT32[(c0 + 3) * 32 + ((p2 + l + 3) & 31)] = d3;
    }
    __syncthreads();

    int cb = t >> 3, pc = t & 7;              // cb 0..63
    #pragma unroll
    for (int j = 0; j < 4; ++j) {
        int col = cb + j * 64;
        int rot = (col >> 2) + (col & 3);
        const unsigned int* base = &sT32[col * 32];
        uint4 o;
        o.x = base[(pc * 4 + 0 + rot) & 31];
        o.y = base[(pc * 4 + 1 + rot) & 31];
        o.z = base[(pc * 4 + 2 + rot) & 31];
        o.w = base[(pc * 4 + 3 + rot) & 31];
        *(uint4*)(Xst + (size_t)col * XP + p0 + pc * 8) = o;
    }
}

// ================= shared device bodies (R2-verified logic) =================

// ---- cov: one (tile, cls, split) -> part tile, software-pipelined ----
static __device__ void cov_body(const unsigned short* Xst, const int* meta, float* part,
                                int tile, int cls, int s,
                                unsigned short (*sA)[72], unsigned short (*sB)[72], int t) {
    int ti = (tile == 2) ? 1 : 0;
    int tj = (tile == 0) ? 0 : 1;
    bool diag = (tile != 1);
    unsigned short (*SB)[72] = diag ? sA : sB;
    int kb = meta[cls];
    int len = meta[cls + 1] - kb;
    int nch = len >> 6;
    int ch0 = (nch * s) / SPL, ch1 = (nch * (s + 1)) / SPL;

    int lane = t & 63, wave = t >> 6;
    int wro = (wave >> 1) * 64, wco = (wave & 1) * 64;
    f32x4 acc[4][4] = {};
    int sr = t >> 1;
    int sq = (t & 1) * 32;

    uint4 a0, a1, a2, a3, b0, b1, b2, b3;
    if (ch0 < ch1) {
        int k0 = kb + ch0 * 64;
        const uint4* ga = (const uint4*)(Xst + (size_t)(ti * 128 + sr) * XP + k0 + sq);
        a0 = ga[0]; a1 = ga[1]; a2 = ga[2]; a3 = ga[3];
        if (!diag) {
            const uint4* gb = (const uint4*)(Xst + (size_t)(tj * 128 + sr) * XP + k0 + sq);
            b0 = gb[0]; b1 = gb[1]; b2 = gb[2]; b3 = gb[3];
        }
    }
    for (int ch = ch0; ch < ch1; ++ch) {
        __syncthreads();
        *(uint4*)&sA[sr][sq]      = a0;
        *(uint4*)&sA[sr][sq + 8]  = a1;
        *(uint4*)&sA[sr][sq + 16] = a2;
        *(uint4*)&sA[sr][sq + 24] = a3;
        if (!diag) {
            *(uint4*)&sB[sr][sq]      = b0;
            *(uint4*)&sB[sr][sq + 8]  = b1;
            *(uint4*)&sB[sr][sq + 16] = b2;
            *(uint4*)&sB[sr][sq + 24] = b3;
        }
        __syncthreads();
        if (ch + 1 < ch1) {
            int k0 = kb + (ch + 1) * 64;
            const uint4* ga = (const uint4*)(Xst + (size_t)(ti * 128 + sr) * XP + k0 + sq);
            a0 = ga[0]; a1 = ga[1]; a2 = ga[2]; a3 = ga[3];
            if (!diag) {
                const uint4* gb = (const uint4*)(Xst + (size_t)(tj * 128 + sr) * XP + k0 + sq);
                b0 = gb[0]; b1 = gb[1]; b2 = gb[2]; b3 = gb[3];
            }
        }
        #pragma unroll
        for (int ks = 0; ks < 64; ks += 32) {
            bf16x8 af[4], bfr[4];
            #pragma unroll
            for (int r = 0; r < 4; ++r)
                af[r] = *(const bf16x8*)&sA[wro + r * 16 + (lane & 15)][ks + (lane >> 4) * 8];
            #pragma unroll
            for (int c2 = 0; c2 < 4; ++c2)
                bfr[c2] = *(const bf16x8*)&SB[wco + c2 * 16 + (lane & 15)][ks + (lane >> 4) * 8];
            #pragma unroll
            for (int r = 0; r < 4; ++r) {
                #pragma unroll
                for (int c2 = 0; c2 < 4; ++c2)
                    acc[r][c2] = __builtin_amdgcn_mfma_f32_16x16x32_bf16(af[r], bfr[c2], acc[r][c2], 0, 0, 0);
            }
        }
    }
    float* po = part + (((size_t)s * NCLASS + cls) * 3 + tile) * 16384;
    int prl = wro + ((lane >> 4) << 2);
    int pcl = wco + (lane & 15);
    #pragma unroll
    for (int r = 0; r < 4; ++r) {
        #pragma unroll
        for (int c2 = 0; c2 < 4; ++c2) {
            #pragma unroll
            for (int v = 0; v < 4; ++v)
                po[(size_t)(prl + r * 16 + v) * 128 + pcl + c2 * 16] = acc[r][c2][v];
        }
    }
}

// ---- merge: one of 240 tasks (cls,tile,row-chunk) ----
static __device__ void merge_body(const float* part, float* cov, int tk, int t) {
    int ux = tk % 30, uy = tk / 30;
    int cls = ux / 3, tile = ux % 3;
    int lr = uy * 16 + (t >> 4);
    int lc = (t & 15) * 8;
    size_t off = (size_t)lr * 128 + lc;
    float4 s0 = make_float4(0.f, 0.f, 0.f, 0.f);
    float4 s1 = make_float4(0.f, 0.f, 0.f, 0.f);
    for (int s = 0; s < SPL; ++s) {
        const float* pb = part + (((size_t)s * NCLASS + cls) * 3 + tile) * 16384;
        float4 a = *(const float4*)(pb + off);
        float4 b = *(const float4*)(pb + off + 4);
        s0.x += a.x; s0.y += a.y; s0.z += a.z; s0.w += a.w;
        s1.x += b.x; s1.y += b.y; s1.z += b.z; s1.w += b.w;
    }
    int gr = (tile == 2 ? 128 : 0) + lr;
    int gc = (tile == 0 ? 0 : 128) + lc;
    float* cb = cov + (size_t)cls * MSZ + (size_t)gr * N_COLS + gc;
    *(float4*)cb = s0;
    *(float4*)(cb + 4) = s1;
}

// ---- prep: one (matrix b, row-group ry): E_b = M_b/c_b - I (bf16) ----
static __device__ void prep_body(const float* cov, const int* meta, float* cvals,
                                 unsigned short* slab, int b, int ry, int t, float* red) {
    float scal = scal_of(b, meta);
    float dsum;
    if (b < NCLASS) dsum = cov[(size_t)b * MSZ + t * 257];
    else {
        dsum = 0.f;
        #pragma unroll
        for (int cl = 0; cl < NCLASS; ++cl) dsum += cov[(size_t)cl * MSZ + t * 257];
    }
    __syncthreads();                 // protect red[] from previous iteration readers
    red[t] = dsum;
    __syncthreads();
    for (int s = 128; s > 0; s >>= 1) {
        if (t < s) red[t] += red[t + s];
        __syncthreads();
    }
    float c = 1.f + scal * red[0] / 256.f;
    if (ry == 0 && t == 0) cvals[b] = c;
    float es = scal / c;
    float dadd = 1.f / c - 1.f;

    int i  = ry * 8 + (t >> 5);
    int cg = (t & 31) * 8;
    bool mb = (i >> 7) > (cg >> 7);
    float v[8];
    if (!mb) {
        size_t off = (size_t)i * N_COLS + cg;
        if (b < NCLASS) {
            float4 a = *(const float4*)(cov + (size_t)b * MSZ + off);
            float4 bq = *(const float4*)(cov + (size_t)b * MSZ + off + 4);
            v[0] = a.x; v[1] = a.y; v[2] = a.z; v[3] = a.w;
            v[4] = bq.x; v[5] = bq.y; v[6] = bq.z; v[7] = bq.w;
        } else {
            #pragma unroll
            for (int jj = 0; jj < 8; ++jj) v[jj] = 0.f;
            #pragma unroll
            for (int cl = 0; cl < NCLASS; ++cl) {
                float4 a = *(const float4*)(cov + (size_t)cl * MSZ + off);
                float4 bq = *(const float4*)(cov + (size_t)cl * MSZ + off + 4);
                v[0] += a.x; v[1] += a.y; v[2] += a.z; v[3] += a.w;
                v[4] += bq.x; v[5] += bq.y; v[6] += bq.z; v[7] += bq.w;
            }
        }
    } else {
        #pragma unroll
        for (int jj = 0; jj < 8; ++jj) {
            size_t off = (size_t)(cg + jj) * N_COLS + i;
            float s;
            if (b < NCLASS) s = cov[(size_t)b * MSZ + off];
            else {
                s = 0.f;
                #pragma unroll
                for (int cl = 0; cl < NCLASS; ++cl) s += cov[(size_t)cl * MSZ + off];
            }
            v[jj] = s;
        }
    }
    unsigned short o[8];
    #pragma unroll
    for (int jj = 0; jj < 8; ++jj)
        o[jj] = f2bf(es * v[jj] + ((cg + jj) == i ? dadd : 0.f));
    uint4 pk;
    pk.x = (unsigned)o[0] | ((unsigned)o[1] << 16);
    pk.y = (unsigned)o[2] | ((unsigned)o[3] << 16);
    pk.z = (unsigned)o[4] | ((unsigned)o[5] << 16);
    pk.w = (unsigned)o[6] | ((unsigned)o[7] << 16);
    *(uint4*)&slab[(size_t)b * MSZ + (size_t)i * N_COLS + cg] = pk;
}

// ---- mm: 128x128 tile of D = A*B (bf16 256x256), software-pipelined ----
static __device__ void mm_body(unsigned short* slab,
                               int ai, int bi, int di, int m, int tile,
                               unsigned short (*sA)[72], unsigned short (*sB)[72], int t) {
    int ti = tile >> 1, tj = tile & 1;
    bool diag = (ai == bi) && (ti == tj);
    const unsigned short* A = slab + ((size_t)ai * 11 + m) * MSZ;
    const unsigned short* B = slab + ((size_t)bi * 11 + m) * MSZ;
    unsigned short* D = slab + ((size_t)di * 11 + m) * MSZ;
    unsigned short (*SB)[72] = diag ? sA : sB;

    int lane = t & 63, wave = t >> 6;
    int wro = (wave >> 1) * 64, wco = (wave & 1) * 64;
    f32x4 acc[4][4] = {};
    int sr = t >> 1;
    int sq = (t & 1) * 32;

    uint4 a0, a1, a2, a3, b0, b1, b2, b3;
    {
        const uint4* ga = (const uint4*)(A + (size_t)(ti * 128 + sr) * N_COLS + sq);
        a0 = ga[0]; a1 = ga[1]; a2 = ga[2]; a3 = ga[3];
        if (!diag) {
            const uint4* gb = (const uint4*)(B + (size_t)(tj * 128 + sr) * N_COLS + sq);
            b0 = gb[0]; b1 = gb[1]; b2 = gb[2]; b3 = gb[3];
        }
    }
    for (int ch = 0; ch < 4; ++ch) {
        __syncthreads();
        *(uint4*)&sA[sr][sq]      = a0;
        *(uint4*)&sA[sr][sq + 8]  = a1;
        *(uint4*)&sA[sr][sq + 16] = a2;
        *(uint4*)&sA[sr][sq + 24] = a3;
        if (!diag) {
            *(uint4*)&sB[sr][sq]      = b0;
            *(uint4*)&sB[sr][sq + 8]  = b1;
            *(uint4*)&sB[sr][sq + 16] = b2;
            *(uint4*)&sB[sr][sq + 24] = b3;
        }
        __syncthreads();
        if (ch < 3) {
            int k0 = (ch + 1) * 64;
            const uint4* ga = (const uint4*)(A + (size_t)(ti * 128 + sr) * N_COLS + k0 + sq);
            a0 = ga[0]; a1 = ga[1]; a2 = ga[2]; a3 = ga[3];
            if (!diag) {
                const uint4* gb = (const uint4*)(B + (size_t)(tj * 128 + sr) * N_COLS + k0 + sq);
                b0 = gb[0]; b1 = gb[1]; b2 = gb[2]; b3 = gb[3];
            }
        }
        #pragma unroll
        for (int ks = 0; ks < 64; ks += 32) {
            bf16x8 af[4], bfr[4];
            #pragma unroll
            for (int r = 0; r < 4; ++r)
                af[r] = *(const bf16x8*)&sA[wro + r * 16 + (lane & 15)][ks + (lane >> 4) * 8];
            #pragma unroll
            for (int c2 = 0; c2 < 4; ++c2)
                bfr[c2] = *(const bf16x8*)&SB[wco + c2 * 16 + (lane & 15)][ks + (lane >> 4) * 8];
            #pragma unroll
            for (int r = 0; r < 4; ++r) {
                #pragma unroll
                for (int c2 = 0; c2 < 4; ++c2)
                    acc[r][c2] = __builtin_amdgcn_mfma_f32_16x16x32_bf16(af[r], bfr[c2], acc[r][c2], 0, 0, 0);
            }
        }
    }
    int prow = ti * 128 + wro + ((lane >> 4) << 2);
    int pcol = tj * 128 + wco + (lane & 15);
    #pragma unroll
    for (int r = 0; r < 4; ++r) {
        #pragma unroll
        for (int c2 = 0; c2 < 4; ++c2) {
            #pragma unroll
            for (int v = 0; v < 4; ++v)
                D[(size_t)(prow + r * 16 + v) * N_COLS + pcol + c2 * 16] = f2bf(acc[r][c2][v]);
        }
    }
}

// ---- trace: one (matrix m, row-group ry) -> atomic partial traces ----
static __device__ void trace_body(const unsigned short* slab, float* traces,
                                  int m, int ry, int t) {
    int r  = ry * 32 + (t >> 3);
    int cs = (t & 7) * 32;
    const unsigned short* E = slab + (size_t)m * MSZ;
    const unsigned short* G = E + (size_t)11 * MSZ;
    const unsigned short* H = E + (size_t)22 * MSZ;
    const unsigned short* K = E + (size_t)33 * MSZ;

    float a0 = 0, a1 = 0, a2 = 0, a3 = 0, a4 = 0, a5 = 0, a6 = 0;
    float t1 = (r >= cs && r < cs + 32) ? bf2f(E[(size_t)r * 257]) : 0.f;
    size_t rb = (size_t)r * N_COLS + cs;
    #pragma unroll
    for (int cg = 0; cg < 32; cg += 8) {
        float e[8], g[8], h[8], k[8];
        unpack8(E + rb + cg, e);
        unpack8(G + rb + cg, g);
        unpack8(H + rb + cg, h);
        unpack8(K + rb + cg, k);
        #pragma unroll
        for (int j = 0; j < 8; ++j) {
            a0 = fmaf(e[j], e[j], a0);
            a1 = fmaf(e[j], g[j], a1);
            a2 = fmaf(g[j], g[j], a2);
            a3 = fmaf(g[j], h[j], a3);
            a4 = fmaf(h[j], h[j], a4);
            a5 = fmaf(h[j], k[j], a5);
            a6 = fmaf(k[j], k[j], a6);
        }
    }
    float vals[8] = {a0, a1, a2, a3, a4, a5, a6, t1};
    #pragma unroll
    for (int v = 0; v < 8; ++v) {
        float x = vals[v];
        #pragma unroll
        for (int d = 32; d > 0; d >>= 1) x += __shfl_down(x, d, 64);
        if ((t & 63) == 0) atomicAdd(&traces[m * 16 + v], x);
    }
}

// ---- finalize: degree-8 series -> out ----
static __device__ void finalize_body(const float* traces, const float* cvals,
                                     const int* meta, float* out) {
    float logdet[11];
    for (int mm = 0; mm < 11; ++mm) {
        float tr[8];
        #pragma unroll
        for (int v = 0; v < 8; ++v)
            tr[v] = __hip_atomic_load(&traces[mm * 16 + v],
                                      __ATOMIC_RELAXED, __HIP_MEMORY_SCOPE_AGENT);
        logdet[mm] = 256.f * __logf(cvals[mm])
                   + tr[7]
                   - tr[0] / 2.f + tr[1] / 3.f - tr[2] / 4.f + tr[3] / 5.f
                   - tr[4] / 6.f + tr[5] / 7.f - tr[6] / 8.f;
    }
    float discrimn = 0.5f * logdet[NCLASS];       // GAM1 == 1 => empi == theo
    float compress = 0.f;
    for (int k = 0; k < NCLASS; ++k) {
        float trp = (float)meta[32 + k] + 1e-8f;
        compress += logdet[k] * trp;
    }
    compress = compress / (float)N_ROWS * 0.5f;
    out[0] = -discrimn + compress;                // GAM2 == 1
    out[1] = discrimn;
    out[2] = compress;
    out[3] = discrimn;
    out[4] = compress;
}

// ================= backend (cooperative, 240 x 256) =================
// phases: cov(480) -> merge(240) -> prep(352) -> G(44) -> H,K(88) -> trace(88) -> finalize
__global__ __launch_bounds__(256, 2) void backend_kernel(const unsigned short* Xst,
                                                         const int* meta,
                                                         float* part,
                                                         float* cov,
                                                         float* cvals,
                                                         float* traces,
                                                         unsigned short* slab,
                                                         float* out) {
    cg::grid_group grid = cg::this_grid();
    __shared__ unsigned short sA[128][72];
    __shared__ unsigned short sB[128][72];
    __shared__ float red[256];
    int task = blockIdx.x, t = threadIdx.x;

    for (int tk = task; tk < 3 * NCLASS * SPL; tk += BE_GRID)
        cov_body(Xst, meta, part, tk % 3, (tk / 3) % NCLASS, tk / 30, sA, sB, t);
    grid.sync();

    merge_body(part, cov, task, t);          // exactly 240 tasks
    grid.sync();

    for (int tk = task; tk < 352; tk += BE_GRID)
        prep_body(cov, meta, cvals, slab, tk % 11, tk / 11, t, red);
    grid.sync();

    if (task < 44) mm_body(slab, 0, 0, 1, task >> 2, task & 3, sA, sB, t);
    grid.sync();

    if (task < 88) {
        int z = task / 44, u = task % 44;
        if (z == 0) mm_body(slab, 0, 1, 2, u >> 2, u & 3, sA, sB, t);
        else        mm_body(slab, 1, 1, 3, u >> 2, u & 3, sA, sB, t);
    }
    grid.sync();

    if (task < 88) trace_body(slab, traces, task % 11, task / 11, t);
    __threadfence();
    grid.sync();

    if (task == 0 && t == 0) finalize_body(traces, cvals, meta, out);
}

// ================= fallback standalone kernels (R2 orchestration) =================
__global__ __launch_bounds__(256) void cov_mfma(const unsigned short* __restrict__ Xst,
                                                const int* __restrict__ meta,
                                                float* __restrict__ part) {
    __shared__ unsigned short sA[128][72];
    __shared__ unsigned short sB[128][72];
    cov_body(Xst, meta, part, blockIdx.x, blockIdx.y, blockIdx.z, sA, sB, threadIdx.x);
}

__global__ __launch_bounds__(256) void merge_kernel(const float* __restrict__ part,
                                                    float* __restrict__ cov) {
    merge_body(part, cov, blockIdx.y * 30 + blockIdx.x, threadIdx.x);
}

__global__ __launch_bounds__(256) void prep_kernel(const float* __restrict__ cov,
                                                   const int* __restrict__ meta,
                                                   float* __restrict__ cvals,
                                                   unsigned short* __restrict__ slab) {
    __shared__ float red[256];
    prep_body(cov, meta, cvals, slab, blockIdx.x, blockIdx.y, threadIdx.x, red);
}

__global__ __launch_bounds__(256) void mm_stage(unsigned short* __restrict__ slab,
                                                int ai0, int bi0, int di0,
                                                int ai1, int bi1, int di1) {
    __shared__ unsigned short sA[128][72];
    __shared__ unsigned short sB[128][72];
    int z = blockIdx.z;
    int ai = z ? ai1 : ai0, bi = z ? bi1 : bi0, di = z ? di1 : di0;
    mm_body(slab, ai, bi, di, blockIdx.y, blockIdx.x, sA, sB, threadIdx.x);
}

__global__ __launch_bounds__(256) void trace_fin_kernel(const unsigned short* __restrict__ slab,
                                                        float* __restrict__ traces,
                                                        const float* __restrict__ cvals,
                                                        const int* __restrict__ meta,
                                                        float* __restrict__ out,
                                                        unsigned int* __restrict__ ctr) {
    trace_body(slab, traces, blockIdx.x, blockIdx.y, threadIdx.x);
    __threadfence();
    __syncthreads();
    if (threadIdx.x == 0) {
        unsigned int prev = atomicAdd(ctr, 1u);
        if (prev == 87u) {
            __threadfence();
            finalize_body(traces, cvals, meta, out);
        }
    }
}

extern "C" void kernel_launch(void* const* d_in, const int* in_sizes, int n_in,
                              void* d_out, int out_size, void* d_ws, size_t ws_size,
                              hipStream_t stream) {
    const float* X = (const float*)d_in[0];
    const int*   Y = (const int*)d_in[1];
    float* out = (float*)d_out;

    char* ws = (char*)d_ws;
    const size_t o_cov   = 0;                        // 10*256*256*4 = 2,621,440
    const size_t o_small = 2621440;                  // cvals(64B) + traces(704B) + ctr(@960)
    const size_t o_meta  = o_small + 1024;           // 64 ints
    const size_t o_blkc  = o_meta + 256;             // 2560 ints
    const size_t o_blkb  = o_blkc + 10240;           // 2560 ints
    const size_t o_order = o_blkb + 10240;           // 65536 ints
    const size_t o_part  = o_order + 262144;         // 16*10*3*16384*4 = 31,457,280
    const size_t o_xst   = o_part + 31457280;        // 256*XP*2 = 33,882,112

    float*          cov      = (float*)(ws + o_cov);
    float*          cvals    = (float*)(ws + o_small);
    float*          traces   = (float*)(ws + o_small + 64);
    unsigned int*   ctr      = (unsigned int*)(ws + o_small + 960);
    unsigned int*   smallz   = (unsigned int*)(ws + o_small);
    int*            meta     = (int*)(ws + o_meta);
    int*            blk_cnt  = (int*)(ws + o_blkc);
    int*            blk_base = (int*)(ws + o_blkb);
    int*            order    = (int*)(ws + o_order);
    float*          part     = (float*)(ws + o_part);
    unsigned short* Xst      = (unsigned short*)(ws + o_xst);
    unsigned short* slab     = Xst;                  // E/G/H/K overlay Xst after cov

    hipLaunchKernelGGL(blkhist_kernel, dim3(256), dim3(256), 0, stream, Y, blk_cnt);
    hipLaunchKernelGGL(scan_kernel, dim3(1), dim3(1024), 0, stream, blk_cnt, meta, blk_base, smallz);
    hipLaunchKernelGGL(order_kernel, dim3(256), dim3(256), 0, stream, Y, blk_base, order);
    hipLaunchKernelGGL(gather_kernel, dim3(XP / 64), dim3(512), 0, stream, X, order, meta, Xst);

    const unsigned short* XstC = Xst;
    void* beArgs[8] = { (void*)&XstC, (void*)&meta, (void*)&part, (void*)&cov,
                        (void*)&cvals, (void*)&traces, (void*)&slab, (void*)&out };
    hipError_t ce = hipLaunchCooperativeKernel(backend_kernel, dim3(BE_GRID), dim3(256),
                                               beArgs, 0, stream);
    if (ce != hipSuccess) {
        // fallback: R2-style individual dispatches (same device bodies)
        hipLaunchKernelGGL(cov_mfma, dim3(3, NCLASS, SPL), dim3(256), 0, stream, Xst, meta, part);
        hipLaunchKernelGGL(merge_kernel, dim3(30, 8), dim3(256), 0, stream, part, cov);
        hipLaunchKernelGGL(prep_kernel, dim3(11, 32), dim3(256), 0, stream, cov, meta, cvals, slab);
        hipLaunchKernelGGL(mm_stage, dim3(4, 11, 1), dim3(256), 0, stream, slab, 0, 0, 1, 0, 0, 1);
        hipLaunchKernelGGL(mm_stage, dim3(4, 11, 2), dim3(256), 0, stream, slab, 0, 1, 2, 1, 1, 3);
        hipLaunchKernelGGL(trace_fin_kernel, dim3(11, 8), dim3(256), 0, stream,
                           slab, traces, cvals, meta, out, ctr);
    }
}

// Round 6
// 262.698 us; speedup vs baseline: 1.4590x; 1.4590x over previous
//
#include <hip/hip_runtime.h>

#define N_ROWS 65536
#define N_COLS 256
#define NCLASS 10
#define XP 66176            // Xst col pitch: 65536 + 10*64 pad
#define SPL 16              // K-splits per (class,tile)
#define MSZ 65536           // 256*256 elements per matrix

typedef __attribute__((ext_vector_type(8))) short bf16x8;
typedef __attribute__((ext_vector_type(4))) float f32x4;

// meta layout (ints): [0..10] off_pad, [16..26] offsets (unpadded), [32..41] counts
// slab layout (bf16): s*11*MSZ + m*MSZ for s in {0:E, 1:G=E^2, 2:H=E^3, 3:K=E^4}
// small region (1024B): [0..63] cvals, [64..767] traces,
//   ctrs at byte 768: [0..29] tile_ctr, [30..40] g_ctr, [41..51] hk_ctr, [52] tr_ctr

static __device__ __forceinline__ unsigned short f2bf(float f) {
    unsigned int u = __float_as_uint(f);
    unsigned int r = (u + 0x7FFFu + ((u >> 16) & 1u)) >> 16;   // RTN-even
    return (unsigned short)r;
}
static __device__ __forceinline__ float bf2f(unsigned short s) {
    return __uint_as_float(((unsigned int)s) << 16);
}
static __device__ __forceinline__ void unpack8(const unsigned short* p, float* f) {
    uint4 u = *(const uint4*)p;
    f[0] = __uint_as_float(u.x << 16); f[1] = __uint_as_float(u.x & 0xffff0000u);
    f[2] = __uint_as_float(u.y << 16); f[3] = __uint_as_float(u.y & 0xffff0000u);
    f[4] = __uint_as_float(u.z << 16); f[5] = __uint_as_float(u.z & 0xffff0000u);
    f[6] = __uint_as_float(u.w << 16); f[7] = __uint_as_float(u.w & 0xffff0000u);
}
static __device__ __forceinline__ float scal_of(int b, const int* meta) {
    if (b < NCLASS) return (float)N_COLS / (((float)meta[32 + b] + 1e-8f) * 0.01f);
    return (float)N_COLS / ((float)N_ROWS * 0.01f);
}
static __device__ __forceinline__ int ld_ctr(const int* p) {
    return __hip_atomic_load(p, __ATOMIC_RELAXED, __HIP_MEMORY_SCOPE_AGENT);
}

// ---------------- Phase A: per-block class histogram (256 blocks) ----------------
__global__ __launch_bounds__(256) void blkhist_kernel(const int* __restrict__ Y,
                                                      int* __restrict__ blk_cnt) {
    __shared__ int h[NCLASS];
    int b = blockIdx.x, t = threadIdx.x;
    if (t < NCLASS) h[t] = 0;
    __syncthreads();
    atomicAdd(&h[Y[b * 256 + t]], 1);
    __syncthreads();
    if (t < NCLASS) blk_cnt[b * NCLASS + t] = h[t];
}

// ---------------- Phase B: scan (wave-per-class shuffle scans, 1 block) ----------------
// Also zeroes the small region (cvals/traces/ctrs) so no separate memset dispatch.
__global__ __launch_bounds__(1024) void scan_kernel(const int* __restrict__ blk_cnt,
                                                    int* __restrict__ meta,
                                                    int* __restrict__ blk_base,
                                                    unsigned int* __restrict__ smallz) {
    int t = threadIdx.x;
    if (t < 256) smallz[t] = 0u;          // zero cvals+traces+ctrs (1024 B)
    int w = t >> 6, l = t & 63;
    __shared__ int tots[16];
    __shared__ int soff_s[16];
    int s0 = 0, s1 = 0, s2 = 0, s3 = 0;
    if (w < NCLASS) {
        s0 = blk_cnt[(l      ) * NCLASS + w];
        s1 = blk_cnt[(l +  64) * NCLASS + w];
        s2 = blk_cnt[(l + 128) * NCLASS + w];
        s3 = blk_cnt[(l + 192) * NCLASS + w];
    }
    int x0 = s0, x1 = s1, x2 = s2, x3 = s3;
    for (int d = 1; d < 64; d <<= 1) {
        int y0 = __shfl_up(x0, d, 64), y1 = __shfl_up(x1, d, 64);
        int y2 = __shfl_up(x2, d, 64), y3 = __shfl_up(x3, d, 64);
        if (l >= d) { x0 += y0; x1 += y1; x2 += y2; x3 += y3; }
    }
    int T0 = __shfl(x0, 63, 64), T1 = __shfl(x1, 63, 64);
    int T2 = __shfl(x2, 63, 64), T3 = __shfl(x3, 63, 64);
    if (w < NCLASS && l == 63) tots[w] = T0 + T1 + T2 + T3;
    __syncthreads();
    if (t == 0) {
        int off = 0, offp = 0;
        for (int c = 0; c < NCLASS; ++c) {
            soff_s[c] = off;
            meta[16 + c] = off;
            meta[c] = offp;
            meta[32 + c] = tots[c];
            off += tots[c];
            offp += (tots[c] + 63) & ~63;
        }
        meta[16 + NCLASS] = off;
        meta[NCLASS] = offp;
    }
    __syncthreads();
    if (w < NCLASS) {
        int base = soff_s[w];
        blk_base[(l      ) * NCLASS + w] = base + x0 - s0;
        blk_base[(l +  64) * NCLASS + w] = base + T0 + x1 - s1;
        blk_base[(l + 128) * NCLASS + w] = base + T0 + T1 + x2 - s2;
        blk_base[(l + 192) * NCLASS + w] = base + T0 + T1 + T2 + x3 - s3;
    }
}

// ---------------- Phase C: build sorted order (256 blocks) ----------------
__global__ __launch_bounds__(256) void order_kernel(const int* __restrict__ Y,
                                                    const int* __restrict__ blk_base,
                                                    int* __restrict__ order) {
    __shared__ int lcur[NCLASS];
    int b = blockIdx.x, t = threadIdx.x;
    if (t < NCLASS) lcur[t] = 0;
    __syncthreads();
    int i = b * 256 + t;
    int y = Y[i];
    int pos = blk_base[b * NCLASS + y] + atomicAdd(&lcur[y], 1);
    order[pos] = i;
}

// ---------------- gather + fp32->bf16 + transpose (rotation-swizzled LDS) ----------------
// 512 threads: 8 waves/block, 4 blocks/CU (LDS 32KB) -> 32 waves/CU resident.
__global__ __launch_bounds__(512) void gather_kernel(const float* __restrict__ X,
                                                     const int* __restrict__ order,
                                                     const int* __restrict__ meta,
                                                     unsigned short* __restrict__ Xst) {
    __shared__ unsigned int sT32[256 * 32];   // 32 KB
    int p0 = blockIdx.x * 64;
    if (p0 >= meta[NCLASS]) return;
    int cls = 0;
    while (p0 >= meta[cls + 1]) ++cls;       // 64-tiles never straddle classes
    int lp0 = p0 - meta[cls];
    int cnt = meta[32 + cls];
    int obase = meta[16 + cls];

    int t = threadIdx.x;
    int w = t >> 6, l = t & 63;

    #pragma unroll
    for (int rp = 0; rp < 4; ++rp) {
        int p2 = w * 4 + rp;                  // 0..31 (pos pair index)
        int lpa = lp0 + p2 * 2;
        int lpb = lpa + 1;
        int ra = (lpa < cnt) ? order[obase + lpa] : -1;   // wave-uniform
        int rb = (lpb < cnt) ? order[obase + lpb] : -1;
        float4 va = make_float4(0.f, 0.f, 0.f, 0.f);
        float4 vb = make_float4(0.f, 0.f, 0.f, 0.f);
        if (ra >= 0) va = *(const float4*)(X + (size_t)ra * N_COLS + l * 4);
        if (rb >= 0) vb = *(const float4*)(X + (size_t)rb * N_COLS + l * 4);
        unsigned int d0 = (unsigned)f2bf(va.x) | ((unsigned)f2bf(vb.x) << 16);
        unsigned int d1 = (unsigned)f2bf(va.y) | ((unsigned)f2bf(vb.y) << 16);
        unsigned int d2 = (unsigned)f2bf(va.z) | ((unsigned)f2bf(vb.z) << 16);
        unsigned int d3 = (unsigned)f2bf(va.w) | ((unsigned)f2bf(vb.w) << 16);
        int c0 = l * 4;
        sT32[(c0 + 0) * 32 + ((p2 + l + 0) & 31)] = d0;
        sT32[(c0 + 1) * 32 + ((p2 + l + 1) & 31)] = d1;
        sT32[(c0 + 2) * 32 + ((p2 + l + 2) & 31)] = d2;
        sT32[(c0 + 3) * 32 + ((p2 + l + 3) & 31)] = d3;
    }
    __syncthreads();

    int cb = t >> 3, pc = t & 7;              // cb 0..63
    #pragma unroll
    for (int j = 0; j < 4; ++j) {
        int col = cb + j * 64;
        int rot = (col >> 2) + (col & 3);
        const unsigned int* base = &sT32[col * 32];
        uint4 o;
        o.x = base[(pc * 4 + 0 + rot) & 31];
        o.y = base[(pc * 4 + 1 + rot) & 31];
        o.z = base[(pc * 4 + 2 + rot) & 31];
        o.w = base[(pc * 4 + 3 + rot) & 31];
        *(uint4*)(Xst + (size_t)col * XP + p0 + pc * 8) = o;
    }
}

// ================= shared device bodies (R5-validated) =================

// ---- cov: one (tile, cls, split) -> part tile, software-pipelined ----
static __device__ void cov_body(const unsigned short* Xst, const int* meta, float* part,
                                int tile, int cls, int s,
                                unsigned short (*sA)[72], unsigned short (*sB)[72], int t) {
    int ti = (tile == 2) ? 1 : 0;
    int tj = (tile == 0) ? 0 : 1;
    bool diag = (tile != 1);
    unsigned short (*SB)[72] = diag ? sA : sB;
    int kb = meta[cls];
    int len = meta[cls + 1] - kb;
    int nch = len >> 6;
    int ch0 = (nch * s) / SPL, ch1 = (nch * (s + 1)) / SPL;

    int lane = t & 63, wave = t >> 6;
    int wro = (wave >> 1) * 64, wco = (wave & 1) * 64;
    f32x4 acc[4][4] = {};
    int sr = t >> 1;
    int sq = (t & 1) * 32;

    uint4 a0, a1, a2, a3, b0, b1, b2, b3;
    if (ch0 < ch1) {
        int k0 = kb + ch0 * 64;
        const uint4* ga = (const uint4*)(Xst + (size_t)(ti * 128 + sr) * XP + k0 + sq);
        a0 = ga[0]; a1 = ga[1]; a2 = ga[2]; a3 = ga[3];
        if (!diag) {
            const uint4* gb = (const uint4*)(Xst + (size_t)(tj * 128 + sr) * XP + k0 + sq);
            b0 = gb[0]; b1 = gb[1]; b2 = gb[2]; b3 = gb[3];
        }
    }
    for (int ch = ch0; ch < ch1; ++ch) {
        __syncthreads();
        *(uint4*)&sA[sr][sq]      = a0;
        *(uint4*)&sA[sr][sq + 8]  = a1;
        *(uint4*)&sA[sr][sq + 16] = a2;
        *(uint4*)&sA[sr][sq + 24] = a3;
        if (!diag) {
            *(uint4*)&sB[sr][sq]      = b0;
            *(uint4*)&sB[sr][sq + 8]  = b1;
            *(uint4*)&sB[sr][sq + 16] = b2;
            *(uint4*)&sB[sr][sq + 24] = b3;
        }
        __syncthreads();
        if (ch + 1 < ch1) {
            int k0 = kb + (ch + 1) * 64;
            const uint4* ga = (const uint4*)(Xst + (size_t)(ti * 128 + sr) * XP + k0 + sq);
            a0 = ga[0]; a1 = ga[1]; a2 = ga[2]; a3 = ga[3];
            if (!diag) {
                const uint4* gb = (const uint4*)(Xst + (size_t)(tj * 128 + sr) * XP + k0 + sq);
                b0 = gb[0]; b1 = gb[1]; b2 = gb[2]; b3 = gb[3];
            }
        }
        #pragma unroll
        for (int ks = 0; ks < 64; ks += 32) {
            bf16x8 af[4], bfr[4];
            #pragma unroll
            for (int r = 0; r < 4; ++r)
                af[r] = *(const bf16x8*)&sA[wro + r * 16 + (lane & 15)][ks + (lane >> 4) * 8];
            #pragma unroll
            for (int c2 = 0; c2 < 4; ++c2)
                bfr[c2] = *(const bf16x8*)&SB[wco + c2 * 16 + (lane & 15)][ks + (lane >> 4) * 8];
            #pragma unroll
            for (int r = 0; r < 4; ++r) {
                #pragma unroll
                for (int c2 = 0; c2 < 4; ++c2)
                    acc[r][c2] = __builtin_amdgcn_mfma_f32_16x16x32_bf16(af[r], bfr[c2], acc[r][c2], 0, 0, 0);
            }
        }
    }
    float* po = part + (((size_t)s * NCLASS + cls) * 3 + tile) * 16384;
    int prl = wro + ((lane >> 4) << 2);
    int pcl = wco + (lane & 15);
    #pragma unroll
    for (int r = 0; r < 4; ++r) {
        #pragma unroll
        for (int c2 = 0; c2 < 4; ++c2) {
            #pragma unroll
            for (int v = 0; v < 4; ++v)
                po[(size_t)(prl + r * 16 + v) * 128 + pcl + c2 * 16] = acc[r][c2][v];
        }
    }
}

// ---- merge: one (tile-unit u, row-chunk) -> cov ----
static __device__ void merge_body(const float* part, float* cov, int tk, int t) {
    int ux = tk % 30, uy = tk / 30;
    int cls = ux / 3, tile = ux % 3;
    int lr = uy * 16 + (t >> 4);
    int lc = (t & 15) * 8;
    size_t off = (size_t)lr * 128 + lc;
    float4 s0 = make_float4(0.f, 0.f, 0.f, 0.f);
    float4 s1 = make_float4(0.f, 0.f, 0.f, 0.f);
    for (int s = 0; s < SPL; ++s) {
        const float* pb = part + (((size_t)s * NCLASS + cls) * 3 + tile) * 16384;
        float4 a = *(const float4*)(pb + off);
        float4 b = *(const float4*)(pb + off + 4);
        s0.x += a.x; s0.y += a.y; s0.z += a.z; s0.w += a.w;
        s1.x += b.x; s1.y += b.y; s1.z += b.z; s1.w += b.w;
    }
    int gr = (tile == 2 ? 128 : 0) + lr;
    int gc = (tile == 0 ? 0 : 128) + lc;
    float* cb = cov + (size_t)cls * MSZ + (size_t)gr * N_COLS + gc;
    *(float4*)cb = s0;
    *(float4*)(cb + 4) = s1;
}

// ---- prep: one (matrix b, row-group ry): E_b = M_b/c_b - I (bf16) ----
static __device__ void prep_body(const float* cov, const int* meta, float* cvals,
                                 unsigned short* slab, int b, int ry, int t, float* red) {
    float scal = scal_of(b, meta);
    float dsum;
    if (b < NCLASS) dsum = cov[(size_t)b * MSZ + t * 257];
    else {
        dsum = 0.f;
        #pragma unroll
        for (int cl = 0; cl < NCLASS; ++cl) dsum += cov[(size_t)cl * MSZ + t * 257];
    }
    red[t] = dsum;
    __syncthreads();
    for (int s = 128; s > 0; s >>= 1) {
        if (t < s) red[t] += red[t + s];
        __syncthreads();
    }
    float c = 1.f + scal * red[0] / 256.f;
    if (ry == 0 && t == 0) cvals[b] = c;
    float es = scal / c;
    float dadd = 1.f / c - 1.f;

    int i  = ry * 8 + (t >> 5);
    int cg = (t & 31) * 8;
    bool mb = (i >> 7) > (cg >> 7);
    float v[8];
    if (!mb) {
        size_t off = (size_t)i * N_COLS + cg;
        if (b < NCLASS) {
            float4 a = *(const float4*)(cov + (size_t)b * MSZ + off);
            float4 bq = *(const float4*)(cov + (size_t)b * MSZ + off + 4);
            v[0] = a.x; v[1] = a.y; v[2] = a.z; v[3] = a.w;
            v[4] = bq.x; v[5] = bq.y; v[6] = bq.z; v[7] = bq.w;
        } else {
            #pragma unroll
            for (int jj = 0; jj < 8; ++jj) v[jj] = 0.f;
            #pragma unroll
            for (int cl = 0; cl < NCLASS; ++cl) {
                float4 a = *(const float4*)(cov + (size_t)cl * MSZ + off);
                float4 bq = *(const float4*)(cov + (size_t)cl * MSZ + off + 4);
                v[0] += a.x; v[1] += a.y; v[2] += a.z; v[3] += a.w;
                v[4] += bq.x; v[5] += bq.y; v[6] += bq.z; v[7] += bq.w;
            }
        }
    } else {
        #pragma unroll
        for (int jj = 0; jj < 8; ++jj) {
            size_t off = (size_t)(cg + jj) * N_COLS + i;
            float s;
            if (b < NCLASS) s = cov[(size_t)b * MSZ + off];
            else {
                s = 0.f;
                #pragma unroll
                for (int cl = 0; cl < NCLASS; ++cl) s += cov[(size_t)cl * MSZ + off];
            }
            v[jj] = s;
        }
    }
    unsigned short o[8];
    #pragma unroll
    for (int jj = 0; jj < 8; ++jj)
        o[jj] = f2bf(es * v[jj] + ((cg + jj) == i ? dadd : 0.f));
    uint4 pk;
    pk.x = (unsigned)o[0] | ((unsigned)o[1] << 16);
    pk.y = (unsigned)o[2] | ((unsigned)o[3] << 16);
    pk.z = (unsigned)o[4] | ((unsigned)o[5] << 16);
    pk.w = (unsigned)o[6] | ((unsigned)o[7] << 16);
    *(uint4*)&slab[(size_t)b * MSZ + (size_t)i * N_COLS + cg] = pk;
}

// ---- mm: 128x128 tile of D = A*B (bf16 256x256), software-pipelined ----
static __device__ void mm_body(unsigned short* slab,
                               int ai, int bi, int di, int m, int tile,
                               unsigned short (*sA)[72], unsigned short (*sB)[72], int t) {
    int ti = tile >> 1, tj = tile & 1;
    bool diag = (ai == bi) && (ti == tj);
    const unsigned short* A = slab + ((size_t)ai * 11 + m) * MSZ;
    const unsigned short* B = slab + ((size_t)bi * 11 + m) * MSZ;
    unsigned short* D = slab + ((size_t)di * 11 + m) * MSZ;
    unsigned short (*SB)[72] = diag ? sA : sB;

    int lane = t & 63, wave = t >> 6;
    int wro = (wave >> 1) * 64, wco = (wave & 1) * 64;
    f32x4 acc[4][4] = {};
    int sr = t >> 1;
    int sq = (t & 1) * 32;

    uint4 a0, a1, a2, a3, b0, b1, b2, b3;
    {
        const uint4* ga = (const uint4*)(A + (size_t)(ti * 128 + sr) * N_COLS + sq);
        a0 = ga[0]; a1 = ga[1]; a2 = ga[2]; a3 = ga[3];
        if (!diag) {
            const uint4* gb = (const uint4*)(B + (size_t)(tj * 128 + sr) * N_COLS + sq);
            b0 = gb[0]; b1 = gb[1]; b2 = gb[2]; b3 = gb[3];
        }
    }
    for (int ch = 0; ch < 4; ++ch) {
        __syncthreads();
        *(uint4*)&sA[sr][sq]      = a0;
        *(uint4*)&sA[sr][sq + 8]  = a1;
        *(uint4*)&sA[sr][sq + 16] = a2;
        *(uint4*)&sA[sr][sq + 24] = a3;
        if (!diag) {
            *(uint4*)&sB[sr][sq]      = b0;
            *(uint4*)&sB[sr][sq + 8]  = b1;
            *(uint4*)&sB[sr][sq + 16] = b2;
            *(uint4*)&sB[sr][sq + 24] = b3;
        }
        __syncthreads();
        if (ch < 3) {
            int k0 = (ch + 1) * 64;
            const uint4* ga = (const uint4*)(A + (size_t)(ti * 128 + sr) * N_COLS + k0 + sq);
            a0 = ga[0]; a1 = ga[1]; a2 = ga[2]; a3 = ga[3];
            if (!diag) {
                const uint4* gb = (const uint4*)(B + (size_t)(tj * 128 + sr) * N_COLS + k0 + sq);
                b0 = gb[0]; b1 = gb[1]; b2 = gb[2]; b3 = gb[3];
            }
        }
        #pragma unroll
        for (int ks = 0; ks < 64; ks += 32) {
            bf16x8 af[4], bfr[4];
            #pragma unroll
            for (int r = 0; r < 4; ++r)
                af[r] = *(const bf16x8*)&sA[wro + r * 16 + (lane & 15)][ks + (lane >> 4) * 8];
            #pragma unroll
            for (int c2 = 0; c2 < 4; ++c2)
                bfr[c2] = *(const bf16x8*)&SB[wco + c2 * 16 + (lane & 15)][ks + (lane >> 4) * 8];
            #pragma unroll
            for (int r = 0; r < 4; ++r) {
                #pragma unroll
                for (int c2 = 0; c2 < 4; ++c2)
                    acc[r][c2] = __builtin_amdgcn_mfma_f32_16x16x32_bf16(af[r], bfr[c2], acc[r][c2], 0, 0, 0);
            }
        }
    }
    int prow = ti * 128 + wro + ((lane >> 4) << 2);
    int pcol = tj * 128 + wco + (lane & 15);
    #pragma unroll
    for (int r = 0; r < 4; ++r) {
        #pragma unroll
        for (int c2 = 0; c2 < 4; ++c2) {
            #pragma unroll
            for (int v = 0; v < 4; ++v)
                D[(size_t)(prow + r * 16 + v) * N_COLS + pcol + c2 * 16] = f2bf(acc[r][c2][v]);
        }
    }
}

// ---- trace: one (matrix m, row-group ry) -> atomic partial traces ----
static __device__ void trace_body(const unsigned short* slab, float* traces,
                                  int m, int ry, int t) {
    int r  = ry * 32 + (t >> 3);
    int cs = (t & 7) * 32;
    const unsigned short* E = slab + (size_t)m * MSZ;
    const unsigned short* G = E + (size_t)11 * MSZ;
    const unsigned short* H = E + (size_t)22 * MSZ;
    const unsigned short* K = E + (size_t)33 * MSZ;

    float a0 = 0, a1 = 0, a2 = 0, a3 = 0, a4 = 0, a5 = 0, a6 = 0;
    float t1 = (r >= cs && r < cs + 32) ? bf2f(E[(size_t)r * 257]) : 0.f;
    size_t rb = (size_t)r * N_COLS + cs;
    #pragma unroll
    for (int cg = 0; cg < 32; cg += 8) {
        float e[8], g[8], h[8], k[8];
        unpack8(E + rb + cg, e);
        unpack8(G + rb + cg, g);
        unpack8(H + rb + cg, h);
        unpack8(K + rb + cg, k);
        #pragma unroll
        for (int j = 0; j < 8; ++j) {
            a0 = fmaf(e[j], e[j], a0);
            a1 = fmaf(e[j], g[j], a1);
            a2 = fmaf(g[j], g[j], a2);
            a3 = fmaf(g[j], h[j], a3);
            a4 = fmaf(h[j], h[j], a4);
            a5 = fmaf(h[j], k[j], a5);
            a6 = fmaf(k[j], k[j], a6);
        }
    }
    float vals[8] = {a0, a1, a2, a3, a4, a5, a6, t1};
    #pragma unroll
    for (int v = 0; v < 8; ++v) {
        float x = vals[v];
        #pragma unroll
        for (int d = 32; d > 0; d >>= 1) x += __shfl_down(x, d, 64);
        if ((t & 63) == 0) atomicAdd(&traces[m * 16 + v], x);
    }
}

// ---- finalize: degree-8 series -> out ----
static __device__ void finalize_body(const float* traces, const float* cvals,
                                     const int* meta, float* out) {
    float logdet[11];
    for (int mm = 0; mm < 11; ++mm) {
        float tr[8];
        #pragma unroll
        for (int v = 0; v < 8; ++v)
            tr[v] = __hip_atomic_load(&traces[mm * 16 + v],
                                      __ATOMIC_RELAXED, __HIP_MEMORY_SCOPE_AGENT);
        logdet[mm] = 256.f * __logf(cvals[mm])
                   + tr[7]
                   - tr[0] / 2.f + tr[1] / 3.f - tr[2] / 4.f + tr[3] / 5.f
                   - tr[4] / 6.f + tr[5] / 7.f - tr[6] / 8.f;
    }
    float discrimn = 0.5f * logdet[NCLASS];       // GAM1 == 1 => empi == theo
    float compress = 0.f;
    for (int k = 0; k < NCLASS; ++k) {
        float trp = (float)meta[32 + k] + 1e-8f;
        compress += logdet[k] * trp;
    }
    compress = compress / (float)N_ROWS * 0.5f;
    out[0] = -discrimn + compress;                // GAM2 == 1
    out[1] = discrimn;
    out[2] = compress;
    out[3] = discrimn;
    out[4] = compress;
}

// ================= covmerge: 720 blocks = 240 merge-waiters + 480 cov producers =========
// Waiters (240) < capacity-1 (>=512 at 2 blocks/CU) -> producers always schedulable ->
// deadlock-free regardless of dispatch order. Producer: syncthreads -> threadfence
// (L2 writeback) -> atomicAdd(tile_ctr). Waiter: spin -> threadfence (L2 inv) -> read.
__global__ __launch_bounds__(256) void covmerge_kernel(const unsigned short* __restrict__ Xst,
                                                       const int* __restrict__ meta,
                                                       float* __restrict__ part,
                                                       float* __restrict__ cov,
                                                       int* __restrict__ ctrs) {
    __shared__ unsigned short sA[128][72];
    __shared__ unsigned short sB[128][72];
    int b = blockIdx.x, t = threadIdx.x;
    if (b < 240) {
        int u = b >> 3, rc = b & 7;          // tile-unit, row-chunk
        if (t == 0) {
            while (ld_ctr(&ctrs[u]) < SPL) __builtin_amdgcn_s_sleep(2);
        }
        __syncthreads();
        __threadfence();                      // acquire: invalidate stale clean lines
        merge_body(part, cov, rc * 30 + u, t);
    } else {
        int b2 = b - 240;
        int tile = b2 % 3, cls = (b2 / 3) % NCLASS, s = b2 / 30;
        cov_body(Xst, meta, part, tile, cls, s, sA, sB, t);
        __syncthreads();                      // all lanes' part stores issued
        if (t == 0) {
            __threadfence();                  // release: write back L2
            atomicAdd(&ctrs[cls * 3 + tile], 1);
        }
    }
}

// ================= prep (grid (11,32)) =================
__global__ __launch_bounds__(256) void prep_kernel(const float* __restrict__ cov,
                                                   const int* __restrict__ meta,
                                                   float* __restrict__ cvals,
                                                   unsigned short* __restrict__ slab) {
    __shared__ float red[256];
    prep_body(cov, meta, cvals, slab, blockIdx.x, blockIdx.y, threadIdx.x, red);
}

// ================= power: mm1(44) + mm2(88) + trace(88) + finalize, 220 blocks =========
// 220 <= 256 CUs -> all blocks co-resident -> flag-waiting is deadlock-free.
// ctrs: [30..40] g_ctr[m], [41..51] hk_ctr[m], [52] trace-done.
__global__ __launch_bounds__(256) void power_kernel(unsigned short* __restrict__ slab,
                                                    float* __restrict__ traces,
                                                    const float* __restrict__ cvals,
                                                    const int* __restrict__ meta,
                                                    float* __restrict__ out,
                                                    int* __restrict__ ctrs) {
    __shared__ unsigned short sA[128][72];
    __shared__ unsigned short sB[128][72];
    int b = blockIdx.x, t = threadIdx.x;

    if (b < 44) {
        // ---- G = E*E ----
        int m = b >> 2;
        mm_body(slab, 0, 0, 1, m, b & 3, sA, sB, t);
        __syncthreads();
        if (t == 0) { __threadfence(); atomicAdd(&ctrs[30 + m], 1); }
    } else if (b < 132) {
        // ---- H = E*G ; K = G*G ----
        int u = b - 44;
        int z = u / 44, q = u % 44;
        int m = q >> 2;
        if (t == 0) {
            while (ld_ctr(&ctrs[30 + m]) < 4) __builtin_amdgcn_s_sleep(2);
        }
        __syncthreads();
        __threadfence();
        if (z == 0) mm_body(slab, 0, 1, 2, m, q & 3, sA, sB, t);
        else        mm_body(slab, 1, 1, 3, m, q & 3, sA, sB, t);
        __syncthreads();
        if (t == 0) { __threadfence(); atomicAdd(&ctrs[41 + m], 1); }
    } else {
        // ---- traces ----
        int u = b - 132;                       // 0..87
        int m = u % 11, ry = u / 11;
        if (t == 0) {
            while (ld_ctr(&ctrs[41 + m]) < 8) __builtin_amdgcn_s_sleep(2);
        }
        __syncthreads();
        __threadfence();
        trace_body(slab, traces, m, ry, t);
        __threadfence();
        __syncthreads();
        if (t == 0) {
            int prev = atomicAdd(&ctrs[52], 1);
            if (prev == 87) {
                __threadfence();
                finalize_body(traces, cvals, meta, out);
            }
        }
    }
}

extern "C" void kernel_launch(void* const* d_in, const int* in_sizes, int n_in,
                              void* d_out, int out_size, void* d_ws, size_t ws_size,
                              hipStream_t stream) {
    const float* X = (const float*)d_in[0];
    const int*   Y = (const int*)d_in[1];
    float* out = (float*)d_out;

    char* ws = (char*)d_ws;
    const size_t o_cov   = 0;                        // 10*256*256*4 = 2,621,440
    const size_t o_small = 2621440;                  // cvals(64B)+traces(704B)+ctrs(@768)
    const size_t o_meta  = o_small + 1024;           // 64 ints
    const size_t o_blkc  = o_meta + 256;             // 2560 ints
    const size_t o_blkb  = o_blkc + 10240;           // 2560 ints
    const size_t o_order = o_blkb + 10240;           // 65536 ints
    const size_t o_part  = o_order + 262144;         // 16*10*3*16384*4 = 31,457,280
    const size_t o_xst   = o_part + 31457280;        // 256*XP*2 = 33,882,112

    float*          cov      = (float*)(ws + o_cov);
    float*          cvals    = (float*)(ws + o_small);
    float*          traces   = (float*)(ws + o_small + 64);
    int*            ctrs     = (int*)(ws + o_small + 768);
    unsigned int*   smallz   = (unsigned int*)(ws + o_small);
    int*            meta     = (int*)(ws + o_meta);
    int*            blk_cnt  = (int*)(ws + o_blkc);
    int*            blk_base = (int*)(ws + o_blkb);
    int*            order    = (int*)(ws + o_order);
    float*          part     = (float*)(ws + o_part);
    unsigned short* Xst      = (unsigned short*)(ws + o_xst);
    unsigned short* slab     = Xst;                  // E/G/H/K overlay Xst after cov

    hipLaunchKernelGGL(blkhist_kernel, dim3(256), dim3(256), 0, stream, Y, blk_cnt);
    hipLaunchKernelGGL(scan_kernel, dim3(1), dim3(1024), 0, stream, blk_cnt, meta, blk_base, smallz);
    hipLaunchKernelGGL(order_kernel, dim3(256), dim3(256), 0, stream, Y, blk_base, order);
    hipLaunchKernelGGL(gather_kernel, dim3(XP / 64), dim3(512), 0, stream, X, order, meta, Xst);
    hipLaunchKernelGGL(covmerge_kernel, dim3(720), dim3(256), 0, stream, Xst, meta, part, cov, ctrs);
    hipLaunchKernelGGL(prep_kernel, dim3(11, 32), dim3(256), 0, stream, cov, meta, cvals, slab);
    hipLaunchKernelGGL(power_kernel, dim3(220), dim3(256), 0, stream, slab, traces, cvals, meta, out, ctrs);
}

// Round 7
// 191.212 us; speedup vs baseline: 2.0045x; 1.3739x over previous
//
#include <hip/hip_runtime.h>

#define N_ROWS 65536
#define N_COLS 256
#define NCLASS 10
#define XP 66176            // Xst col pitch: 65536 + 10*64 pad
#define SPL 16              // K-splits per (class,tile)
#define MSZ 65536           // 256*256 elements per matrix

typedef __attribute__((ext_vector_type(8))) short bf16x8;
typedef __attribute__((ext_vector_type(4))) float f32x4;

// meta layout (ints): [0..10] off_pad, [16..26] offsets (unpadded), [32..41] counts
// slab layout (bf16): s*11*MSZ + m*MSZ for s in {0:E, 1:G=E^2, 2:H=E^3, 3:K=E^4}
// small region (1024B): [64..767] traces, ints@768: [0..10] unused, [30..40] g_ctr,
//   [41..51] hk_ctr, [52] tr_ctr; floats@832: cvals_raw[0..10] (diag sums)

static __device__ __forceinline__ unsigned short f2bf(float f) {
    unsigned int u = __float_as_uint(f);
    unsigned int r = (u + 0x7FFFu + ((u >> 16) & 1u)) >> 16;   // RTN-even
    return (unsigned short)r;
}
static __device__ __forceinline__ float bf2f(unsigned short s) {
    return __uint_as_float(((unsigned int)s) << 16);
}
static __device__ __forceinline__ void unpack8(const unsigned short* p, float* f) {
    uint4 u = *(const uint4*)p;
    f[0] = __uint_as_float(u.x << 16); f[1] = __uint_as_float(u.x & 0xffff0000u);
    f[2] = __uint_as_float(u.y << 16); f[3] = __uint_as_float(u.y & 0xffff0000u);
    f[4] = __uint_as_float(u.z << 16); f[5] = __uint_as_float(u.z & 0xffff0000u);
    f[6] = __uint_as_float(u.w << 16); f[7] = __uint_as_float(u.w & 0xffff0000u);
}
static __device__ __forceinline__ float scal_of(int b, const int* meta) {
    if (b < NCLASS) return (float)N_COLS / (((float)meta[32 + b] + 1e-8f) * 0.01f);
    return (float)N_COLS / ((float)N_ROWS * 0.01f);
}
static __device__ __forceinline__ int ld_ctr(const int* p) {
    return __hip_atomic_load(p, __ATOMIC_RELAXED, __HIP_MEMORY_SCOPE_AGENT);
}

// ---------------- Phase A: per-block class histogram (256 blocks) ----------------
__global__ __launch_bounds__(256) void blkhist_kernel(const int* __restrict__ Y,
                                                      int* __restrict__ blk_cnt) {
    __shared__ int h[NCLASS];
    int b = blockIdx.x, t = threadIdx.x;
    if (t < NCLASS) h[t] = 0;
    __syncthreads();
    atomicAdd(&h[Y[b * 256 + t]], 1);
    __syncthreads();
    if (t < NCLASS) blk_cnt[b * NCLASS + t] = h[t];
}

// ---------------- Phase B: scan (wave-per-class shuffle scans, 1 block) ----------------
// Also zeroes the small region (traces/ctrs/cvals_raw) so no separate memset dispatch.
__global__ __launch_bounds__(1024) void scan_kernel(const int* __restrict__ blk_cnt,
                                                    int* __restrict__ meta,
                                                    int* __restrict__ blk_base,
                                                    unsigned int* __restrict__ smallz) {
    int t = threadIdx.x;
    if (t < 256) smallz[t] = 0u;          // zero traces+ctrs+cvals_raw (1024 B)
    int w = t >> 6, l = t & 63;
    __shared__ int tots[16];
    __shared__ int soff_s[16];
    int s0 = 0, s1 = 0, s2 = 0, s3 = 0;
    if (w < NCLASS) {
        s0 = blk_cnt[(l      ) * NCLASS + w];
        s1 = blk_cnt[(l +  64) * NCLASS + w];
        s2 = blk_cnt[(l + 128) * NCLASS + w];
        s3 = blk_cnt[(l + 192) * NCLASS + w];
    }
    int x0 = s0, x1 = s1, x2 = s2, x3 = s3;
    for (int d = 1; d < 64; d <<= 1) {
        int y0 = __shfl_up(x0, d, 64), y1 = __shfl_up(x1, d, 64);
        int y2 = __shfl_up(x2, d, 64), y3 = __shfl_up(x3, d, 64);
        if (l >= d) { x0 += y0; x1 += y1; x2 += y2; x3 += y3; }
    }
    int T0 = __shfl(x0, 63, 64), T1 = __shfl(x1, 63, 64);
    int T2 = __shfl(x2, 63, 64), T3 = __shfl(x3, 63, 64);
    if (w < NCLASS && l == 63) tots[w] = T0 + T1 + T2 + T3;
    __syncthreads();
    if (t == 0) {
        int off = 0, offp = 0;
        for (int c = 0; c < NCLASS; ++c) {
            soff_s[c] = off;
            meta[16 + c] = off;
            meta[c] = offp;
            meta[32 + c] = tots[c];
            off += tots[c];
            offp += (tots[c] + 63) & ~63;
        }
        meta[16 + NCLASS] = off;
        meta[NCLASS] = offp;
    }
    __syncthreads();
    if (w < NCLASS) {
        int base = soff_s[w];
        blk_base[(l      ) * NCLASS + w] = base + x0 - s0;
        blk_base[(l +  64) * NCLASS + w] = base + T0 + x1 - s1;
        blk_base[(l + 128) * NCLASS + w] = base + T0 + T1 + x2 - s2;
        blk_base[(l + 192) * NCLASS + w] = base + T0 + T1 + T2 + x3 - s3;
    }
}

// ---------------- Phase C: build sorted order (256 blocks) ----------------
__global__ __launch_bounds__(256) void order_kernel(const int* __restrict__ Y,
                                                    const int* __restrict__ blk_base,
                                                    int* __restrict__ order) {
    __shared__ int lcur[NCLASS];
    int b = blockIdx.x, t = threadIdx.x;
    if (t < NCLASS) lcur[t] = 0;
    __syncthreads();
    int i = b * 256 + t;
    int y = Y[i];
    int pos = blk_base[b * NCLASS + y] + atomicAdd(&lcur[y], 1);
    order[pos] = i;
}

// ---------------- gather + fp32->bf16 + transpose (rotation-swizzled LDS) ----------------
// 512 threads: 8 waves/block, 4 blocks/CU (LDS 32KB) -> 32 waves/CU resident.
__global__ __launch_bounds__(512) void gather_kernel(const float* __restrict__ X,
                                                     const int* __restrict__ order,
                                                     const int* __restrict__ meta,
                                                     unsigned short* __restrict__ Xst) {
    __shared__ unsigned int sT32[256 * 32];   // 32 KB
    int p0 = blockIdx.x * 64;
    if (p0 >= meta[NCLASS]) return;
    int cls = 0;
    while (p0 >= meta[cls + 1]) ++cls;       // 64-tiles never straddle classes
    int lp0 = p0 - meta[cls];
    int cnt = meta[32 + cls];
    int obase = meta[16 + cls];

    int t = threadIdx.x;
    int w = t >> 6, l = t & 63;

    #pragma unroll
    for (int rp = 0; rp < 4; ++rp) {
        int p2 = w * 4 + rp;                  // 0..31 (pos pair index)
        int lpa = lp0 + p2 * 2;
        int lpb = lpa + 1;
        int ra = (lpa < cnt) ? order[obase + lpa] : -1;   // wave-uniform
        int rb = (lpb < cnt) ? order[obase + lpb] : -1;
        float4 va = make_float4(0.f, 0.f, 0.f, 0.f);
        float4 vb = make_float4(0.f, 0.f, 0.f, 0.f);
        if (ra >= 0) va = *(const float4*)(X + (size_t)ra * N_COLS + l * 4);
        if (rb >= 0) vb = *(const float4*)(X + (size_t)rb * N_COLS + l * 4);
        unsigned int d0 = (unsigned)f2bf(va.x) | ((unsigned)f2bf(vb.x) << 16);
        unsigned int d1 = (unsigned)f2bf(va.y) | ((unsigned)f2bf(vb.y) << 16);
        unsigned int d2 = (unsigned)f2bf(va.z) | ((unsigned)f2bf(vb.z) << 16);
        unsigned int d3 = (unsigned)f2bf(va.w) | ((unsigned)f2bf(vb.w) << 16);
        int c0 = l * 4;
        sT32[(c0 + 0) * 32 + ((p2 + l + 0) & 31)] = d0;
        sT32[(c0 + 1) * 32 + ((p2 + l + 1) & 31)] = d1;
        sT32[(c0 + 2) * 32 + ((p2 + l + 2) & 31)] = d2;
        sT32[(c0 + 3) * 32 + ((p2 + l + 3) & 31)] = d3;
    }
    __syncthreads();

    int cb = t >> 3, pc = t & 7;              // cb 0..63
    #pragma unroll
    for (int j = 0; j < 4; ++j) {
        int col = cb + j * 64;
        int rot = (col >> 2) + (col & 3);
        const unsigned int* base = &sT32[col * 32];
        uint4 o;
        o.x = base[(pc * 4 + 0 + rot) & 31];
        o.y = base[(pc * 4 + 1 + rot) & 31];
        o.z = base[(pc * 4 + 2 + rot) & 31];
        o.w = base[(pc * 4 + 3 + rot) & 31];
        *(uint4*)(Xst + (size_t)col * XP + p0 + pc * 8) = o;
    }
}

// ---------------- cov via bf16 MFMA syrk -> per-split partial tiles ----------------
// Software-pipelined (R2-validated); diagonal tiles stage one LDS panel.
__global__ __launch_bounds__(256) void cov_mfma(const unsigned short* __restrict__ Xst,
                                                const int* __restrict__ meta,
                                                float* __restrict__ part) {
    __shared__ unsigned short sA[128][72];
    __shared__ unsigned short sB[128][72];
    int cls = blockIdx.y;
    int tile = blockIdx.x;
    int ti = (tile == 2) ? 1 : 0;
    int tj = (tile == 0) ? 0 : 1;
    bool diag = (tile != 1);
    unsigned short (*SB)[72] = diag ? sA : sB;
    int kb = meta[cls];
    int len = meta[cls + 1] - kb;
    int nch = len >> 6;
    int s = blockIdx.z;
    int ch0 = (nch * s) / SPL, ch1 = (nch * (s + 1)) / SPL;

    int t = threadIdx.x;
    int lane = t & 63, wave = t >> 6;
    int wro = (wave >> 1) * 64, wco = (wave & 1) * 64;

    f32x4 acc[4][4] = {};
    int sr = t >> 1;
    int sq = (t & 1) * 32;

    uint4 a0, a1, a2, a3, b0, b1, b2, b3;
    if (ch0 < ch1) {
        int k0 = kb + ch0 * 64;
        const uint4* ga = (const uint4*)(Xst + (size_t)(ti * 128 + sr) * XP + k0 + sq);
        a0 = ga[0]; a1 = ga[1]; a2 = ga[2]; a3 = ga[3];
        if (!diag) {
            const uint4* gb = (const uint4*)(Xst + (size_t)(tj * 128 + sr) * XP + k0 + sq);
            b0 = gb[0]; b1 = gb[1]; b2 = gb[2]; b3 = gb[3];
        }
    }
    for (int ch = ch0; ch < ch1; ++ch) {
        __syncthreads();
        *(uint4*)&sA[sr][sq]      = a0;
        *(uint4*)&sA[sr][sq + 8]  = a1;
        *(uint4*)&sA[sr][sq + 16] = a2;
        *(uint4*)&sA[sr][sq + 24] = a3;
        if (!diag) {
            *(uint4*)&sB[sr][sq]      = b0;
            *(uint4*)&sB[sr][sq + 8]  = b1;
            *(uint4*)&sB[sr][sq + 16] = b2;
            *(uint4*)&sB[sr][sq + 24] = b3;
        }
        __syncthreads();
        if (ch + 1 < ch1) {
            int k0 = kb + (ch + 1) * 64;
            const uint4* ga = (const uint4*)(Xst + (size_t)(ti * 128 + sr) * XP + k0 + sq);
            a0 = ga[0]; a1 = ga[1]; a2 = ga[2]; a3 = ga[3];
            if (!diag) {
                const uint4* gb = (const uint4*)(Xst + (size_t)(tj * 128 + sr) * XP + k0 + sq);
                b0 = gb[0]; b1 = gb[1]; b2 = gb[2]; b3 = gb[3];
            }
        }
        #pragma unroll
        for (int ks = 0; ks < 64; ks += 32) {
            bf16x8 af[4], bfr[4];
            #pragma unroll
            for (int r = 0; r < 4; ++r)
                af[r] = *(const bf16x8*)&sA[wro + r * 16 + (lane & 15)][ks + (lane >> 4) * 8];
            #pragma unroll
            for (int c2 = 0; c2 < 4; ++c2)
                bfr[c2] = *(const bf16x8*)&SB[wco + c2 * 16 + (lane & 15)][ks + (lane >> 4) * 8];
            #pragma unroll
            for (int r = 0; r < 4; ++r) {
                #pragma unroll
                for (int c2 = 0; c2 < 4; ++c2)
                    acc[r][c2] = __builtin_amdgcn_mfma_f32_16x16x32_bf16(af[r], bfr[c2], acc[r][c2], 0, 0, 0);
            }
        }
    }

    float* po = part + (((size_t)s * NCLASS + cls) * 3 + tile) * 16384;
    int prl = wro + ((lane >> 4) << 2);
    int pcl = wco + (lane & 15);
    #pragma unroll
    for (int r = 0; r < 4; ++r) {
        #pragma unroll
        for (int c2 = 0; c2 < 4; ++c2) {
            #pragma unroll
            for (int v = 0; v < 4; ++v)
                po[(size_t)(prl + r * 16 + v) * 128 + pcl + c2 * 16] = acc[r][c2][v];
        }
    }
}

// ---------------- merge: sum SPL partials -> cov, + diagonal trace sums ----------------
// grid (30, 8). Diagonal values are in-register here, so the per-class trace
// (needed for c_b) is computed via one block reduce + 2 atomics, removing prep's
// 32x-redundant strided diagonal re-read.
__global__ __launch_bounds__(256) void merge_kernel(const float* __restrict__ part,
                                                    float* __restrict__ cov,
                                                    float* __restrict__ cvals_raw) {
    __shared__ float red[256];
    int u = blockIdx.x;
    int cls = u / 3, tile = u % 3;
    int t = threadIdx.x;
    int lr = blockIdx.y * 16 + (t >> 4);   // local row 0..127
    int lc = (t & 15) * 8;                 // local col
    size_t off = (size_t)lr * 128 + lc;
    float4 s0 = make_float4(0.f, 0.f, 0.f, 0.f);
    float4 s1 = make_float4(0.f, 0.f, 0.f, 0.f);
    for (int s = 0; s < SPL; ++s) {
        const float* pb = part + (((size_t)s * NCLASS + cls) * 3 + tile) * 16384;
        float4 a = *(const float4*)(pb + off);
        float4 b = *(const float4*)(pb + off + 4);
        s0.x += a.x; s0.y += a.y; s0.z += a.z; s0.w += a.w;
        s1.x += b.x; s1.y += b.y; s1.z += b.z; s1.w += b.w;
    }
    int gr = (tile == 2 ? 128 : 0) + lr;
    int gc = (tile == 0 ? 0 : 128) + lc;
    float* cb = cov + (size_t)cls * MSZ + (size_t)gr * N_COLS + gc;
    *(float4*)cb = s0;
    *(float4*)(cb + 4) = s1;

    if (tile != 1) {                       // tiles (0,0) and (1,1) hold the diagonal
        float dval = 0.f;
        int j = lr - lc;
        if      (j == 0) dval = s0.x; else if (j == 1) dval = s0.y;
        else if (j == 2) dval = s0.z; else if (j == 3) dval = s0.w;
        else if (j == 4) dval = s1.x; else if (j == 5) dval = s1.y;
        else if (j == 6) dval = s1.z; else if (j == 7) dval = s1.w;
        red[t] = dval;
        __syncthreads();
        for (int st = 128; st > 0; st >>= 1) {
            if (t < st) red[t] += red[t + st];
            __syncthreads();
        }
        if (t == 0) {
            atomicAdd(&cvals_raw[cls], red[0]);
            atomicAdd(&cvals_raw[10], red[0]);
        }
    }
}

// ---------------- prep: E_b = M_b/c_b - I (bf16); grid (11, 32), pure streaming ----------------
__global__ __launch_bounds__(256) void prep_kernel(const float* __restrict__ cov,
                                                   const int* __restrict__ meta,
                                                   const float* __restrict__ cvals_raw,
                                                   unsigned short* __restrict__ slab) {
    int b = blockIdx.x;   // matrix 0..10
    int t = threadIdx.x;
    float scal = scal_of(b, meta);
    float raw = cvals_raw[b < NCLASS ? b : 10];
    float c = 1.f + scal * raw / 256.f;
    float es = scal / c;
    float dadd = 1.f / c - 1.f;

    int i  = blockIdx.y * 8 + (t >> 5);   // row
    int cg = (t & 31) * 8;                // col group (8 elems)
    bool mb = (i >> 7) > (cg >> 7);       // cov stores upper 128-blocks; mirror (1,0)
    float v[8];
    if (!mb) {
        size_t off = (size_t)i * N_COLS + cg;
        if (b < NCLASS) {
            float4 a = *(const float4*)(cov + (size_t)b * MSZ + off);
            float4 bq = *(const float4*)(cov + (size_t)b * MSZ + off + 4);
            v[0] = a.x; v[1] = a.y; v[2] = a.z; v[3] = a.w;
            v[4] = bq.x; v[5] = bq.y; v[6] = bq.z; v[7] = bq.w;
        } else {
            #pragma unroll
            for (int jj = 0; jj < 8; ++jj) v[jj] = 0.f;
            #pragma unroll
            for (int cl = 0; cl < NCLASS; ++cl) {
                float4 a = *(const float4*)(cov + (size_t)cl * MSZ + off);
                float4 bq = *(const float4*)(cov + (size_t)cl * MSZ + off + 4);
                v[0] += a.x; v[1] += a.y; v[2] += a.z; v[3] += a.w;
                v[4] += bq.x; v[5] += bq.y; v[6] += bq.z; v[7] += bq.w;
            }
        }
    } else {
        #pragma unroll
        for (int jj = 0; jj < 8; ++jj) {
            size_t off = (size_t)(cg + jj) * N_COLS + i;
            float s;
            if (b < NCLASS) s = cov[(size_t)b * MSZ + off];
            else {
                s = 0.f;
                #pragma unroll
                for (int cl = 0; cl < NCLASS; ++cl) s += cov[(size_t)cl * MSZ + off];
            }
            v[jj] = s;
        }
    }
    unsigned short o[8];
    #pragma unroll
    for (int jj = 0; jj < 8; ++jj)
        o[jj] = f2bf(es * v[jj] + ((cg + jj) == i ? dadd : 0.f));
    uint4 pk;
    pk.x = (unsigned)o[0] | ((unsigned)o[1] << 16);
    pk.y = (unsigned)o[2] | ((unsigned)o[3] << 16);
    pk.z = (unsigned)o[4] | ((unsigned)o[5] << 16);
    pk.w = (unsigned)o[6] | ((unsigned)o[7] << 16);
    *(uint4*)&slab[(size_t)b * MSZ + (size_t)i * N_COLS + cg] = pk;
}

// ---- mm: 128x128 tile of D = A*B (bf16 256x256), software-pipelined ----
static __device__ void mm_body(unsigned short* slab,
                               int ai, int bi, int di, int m, int tile,
                               unsigned short (*sA)[72], unsigned short (*sB)[72], int t) {
    int ti = tile >> 1, tj = tile & 1;
    bool diag = (ai == bi) && (ti == tj);
    const unsigned short* A = slab + ((size_t)ai * 11 + m) * MSZ;
    const unsigned short* B = slab + ((size_t)bi * 11 + m) * MSZ;
    unsigned short* D = slab + ((size_t)di * 11 + m) * MSZ;
    unsigned short (*SB)[72] = diag ? sA : sB;

    int lane = t & 63, wave = t >> 6;
    int wro = (wave >> 1) * 64, wco = (wave & 1) * 64;
    f32x4 acc[4][4] = {};
    int sr = t >> 1;
    int sq = (t & 1) * 32;

    uint4 a0, a1, a2, a3, b0, b1, b2, b3;
    {
        const uint4* ga = (const uint4*)(A + (size_t)(ti * 128 + sr) * N_COLS + sq);
        a0 = ga[0]; a1 = ga[1]; a2 = ga[2]; a3 = ga[3];
        if (!diag) {
            const uint4* gb = (const uint4*)(B + (size_t)(tj * 128 + sr) * N_COLS + sq);
            b0 = gb[0]; b1 = gb[1]; b2 = gb[2]; b3 = gb[3];
        }
    }
    for (int ch = 0; ch < 4; ++ch) {
        __syncthreads();
        *(uint4*)&sA[sr][sq]      = a0;
        *(uint4*)&sA[sr][sq + 8]  = a1;
        *(uint4*)&sA[sr][sq + 16] = a2;
        *(uint4*)&sA[sr][sq + 24] = a3;
        if (!diag) {
            *(uint4*)&sB[sr][sq]      = b0;
            *(uint4*)&sB[sr][sq + 8]  = b1;
            *(uint4*)&sB[sr][sq + 16] = b2;
            *(uint4*)&sB[sr][sq + 24] = b3;
        }
        __syncthreads();
        if (ch < 3) {
            int k0 = (ch + 1) * 64;
            const uint4* ga = (const uint4*)(A + (size_t)(ti * 128 + sr) * N_COLS + k0 + sq);
            a0 = ga[0]; a1 = ga[1]; a2 = ga[2]; a3 = ga[3];
            if (!diag) {
                const uint4* gb = (const uint4*)(B + (size_t)(tj * 128 + sr) * N_COLS + k0 + sq);
                b0 = gb[0]; b1 = gb[1]; b2 = gb[2]; b3 = gb[3];
            }
        }
        #pragma unroll
        for (int ks = 0; ks < 64; ks += 32) {
            bf16x8 af[4], bfr[4];
            #pragma unroll
            for (int r = 0; r < 4; ++r)
                af[r] = *(const bf16x8*)&sA[wro + r * 16 + (lane & 15)][ks + (lane >> 4) * 8];
            #pragma unroll
            for (int c2 = 0; c2 < 4; ++c2)
                bfr[c2] = *(const bf16x8*)&SB[wco + c2 * 16 + (lane & 15)][ks + (lane >> 4) * 8];
            #pragma unroll
            for (int r = 0; r < 4; ++r) {
                #pragma unroll
                for (int c2 = 0; c2 < 4; ++c2)
                    acc[r][c2] = __builtin_amdgcn_mfma_f32_16x16x32_bf16(af[r], bfr[c2], acc[r][c2], 0, 0, 0);
            }
        }
    }
    int prow = ti * 128 + wro + ((lane >> 4) << 2);
    int pcol = tj * 128 + wco + (lane & 15);
    #pragma unroll
    for (int r = 0; r < 4; ++r) {
        #pragma unroll
        for (int c2 = 0; c2 < 4; ++c2) {
            #pragma unroll
            for (int v = 0; v < 4; ++v)
                D[(size_t)(prow + r * 16 + v) * N_COLS + pcol + c2 * 16] = f2bf(acc[r][c2][v]);
        }
    }
}

// ---- trace: one (matrix m, row-group ry) -> atomic partial traces ----
static __device__ void trace_body(const unsigned short* slab, float* traces,
                                  int m, int ry, int t) {
    int r  = ry * 32 + (t >> 3);
    int cs = (t & 7) * 32;
    const unsigned short* E = slab + (size_t)m * MSZ;
    const unsigned short* G = E + (size_t)11 * MSZ;
    const unsigned short* H = E + (size_t)22 * MSZ;
    const unsigned short* K = E + (size_t)33 * MSZ;

    float a0 = 0, a1 = 0, a2 = 0, a3 = 0, a4 = 0, a5 = 0, a6 = 0;
    float t1 = (r >= cs && r < cs + 32) ? bf2f(E[(size_t)r * 257]) : 0.f;
    size_t rb = (size_t)r * N_COLS + cs;
    #pragma unroll
    for (int cg = 0; cg < 32; cg += 8) {
        float e[8], g[8], h[8], k[8];
        unpack8(E + rb + cg, e);
        unpack8(G + rb + cg, g);
        unpack8(H + rb + cg, h);
        unpack8(K + rb + cg, k);
        #pragma unroll
        for (int j = 0; j < 8; ++j) {
            a0 = fmaf(e[j], e[j], a0);
            a1 = fmaf(e[j], g[j], a1);
            a2 = fmaf(g[j], g[j], a2);
            a3 = fmaf(g[j], h[j], a3);
            a4 = fmaf(h[j], h[j], a4);
            a5 = fmaf(h[j], k[j], a5);
            a6 = fmaf(k[j], k[j], a6);
        }
    }
    float vals[8] = {a0, a1, a2, a3, a4, a5, a6, t1};
    #pragma unroll
    for (int v = 0; v < 8; ++v) {
        float x = vals[v];
        #pragma unroll
        for (int d = 32; d > 0; d >>= 1) x += __shfl_down(x, d, 64);
        if ((t & 63) == 0) atomicAdd(&traces[m * 16 + v], x);
    }
}

// ---- finalize: degree-8 series -> out (c_b rebuilt from cvals_raw) ----
static __device__ void finalize_body(const float* traces, const float* cvals_raw,
                                     const int* meta, float* out) {
    float logdet[11];
    for (int mm = 0; mm < 11; ++mm) {
        float tr[8];
        #pragma unroll
        for (int v = 0; v < 8; ++v)
            tr[v] = __hip_atomic_load(&traces[mm * 16 + v],
                                      __ATOMIC_RELAXED, __HIP_MEMORY_SCOPE_AGENT);
        float raw = __hip_atomic_load(&cvals_raw[mm < NCLASS ? mm : 10],
                                      __ATOMIC_RELAXED, __HIP_MEMORY_SCOPE_AGENT);
        float c = 1.f + scal_of(mm, meta) * raw / 256.f;
        logdet[mm] = 256.f * __logf(c)
                   + tr[7]
                   - tr[0] / 2.f + tr[1] / 3.f - tr[2] / 4.f + tr[3] / 5.f
                   - tr[4] / 6.f + tr[5] / 7.f - tr[6] / 8.f;
    }
    float discrimn = 0.5f * logdet[NCLASS];       // GAM1 == 1 => empi == theo
    float compress = 0.f;
    for (int k = 0; k < NCLASS; ++k) {
        float trp = (float)meta[32 + k] + 1e-8f;
        compress += logdet[k] * trp;
    }
    compress = compress / (float)N_ROWS * 0.5f;
    out[0] = -discrimn + compress;                // GAM2 == 1
    out[1] = discrimn;
    out[2] = compress;
    out[3] = discrimn;
    out[4] = compress;
}

// ================= power: mm1(44) + mm2(88) + trace(88) + finalize, 220 blocks =========
// 220 <= 256 CUs -> all co-resident; waits are short (producer = 4-8 blocks of the
// SAME matrix, running concurrently). R6-validated correct. ctrs ints:
// [30..40] g_ctr[m], [41..51] hk_ctr[m], [52] trace-done.
__global__ __launch_bounds__(256) void power_kernel(unsigned short* __restrict__ slab,
                                                    float* __restrict__ traces,
                                                    const float* __restrict__ cvals_raw,
                                                    const int* __restrict__ meta,
                                                    float* __restrict__ out,
                                                    int* __restrict__ ctrs) {
    __shared__ unsigned short sA[128][72];
    __shared__ unsigned short sB[128][72];
    int b = blockIdx.x, t = threadIdx.x;

    if (b < 44) {
        // ---- G = E*E ----
        int m = b >> 2;
        mm_body(slab, 0, 0, 1, m, b & 3, sA, sB, t);
        __syncthreads();
        if (t == 0) { __threadfence(); atomicAdd(&ctrs[30 + m], 1); }
    } else if (b < 132) {
        // ---- H = E*G ; K = G*G ----
        int u = b - 44;
        int z = u / 44, q = u % 44;
        int m = q >> 2;
        if (t == 0) {
            while (ld_ctr(&ctrs[30 + m]) < 4) __builtin_amdgcn_s_sleep(2);
        }
        __syncthreads();
        __threadfence();
        if (z == 0) mm_body(slab, 0, 1, 2, m, q & 3, sA, sB, t);
        else        mm_body(slab, 1, 1, 3, m, q & 3, sA, sB, t);
        __syncthreads();
        if (t == 0) { __threadfence(); atomicAdd(&ctrs[41 + m], 1); }
    } else {
        // ---- traces + finalize ----
        int u = b - 132;                       // 0..87
        int m = u % 11, ry = u / 11;
        if (t == 0) {
            while (ld_ctr(&ctrs[41 + m]) < 8) __builtin_amdgcn_s_sleep(2);
        }
        __syncthreads();
        __threadfence();
        trace_body(slab, traces, m, ry, t);
        __threadfence();
        __syncthreads();
        if (t == 0) {
            int prev = atomicAdd(&ctrs[52], 1);
            if (prev == 87) {
                __threadfence();
                finalize_body(traces, cvals_raw, meta, out);
            }
        }
    }
}

extern "C" void kernel_launch(void* const* d_in, const int* in_sizes, int n_in,
                              void* d_out, int out_size, void* d_ws, size_t ws_size,
                              hipStream_t stream) {
    const float* X = (const float*)d_in[0];
    const int*   Y = (const int*)d_in[1];
    float* out = (float*)d_out;

    char* ws = (char*)d_ws;
    const size_t o_cov   = 0;                        // 10*256*256*4 = 2,621,440
    const size_t o_small = 2621440;                  // traces@64, ctrs@768, cvals_raw@832
    const size_t o_meta  = o_small + 1024;           // 64 ints
    const size_t o_blkc  = o_meta + 256;             // 2560 ints
    const size_t o_blkb  = o_blkc + 10240;           // 2560 ints
    const size_t o_order = o_blkb + 10240;           // 65536 ints
    const size_t o_part  = o_order + 262144;         // 16*10*3*16384*4 = 31,457,280
    const size_t o_xst   = o_part + 31457280;        // 256*XP*2 = 33,882,112

    float*          cov      = (float*)(ws + o_cov);
    float*          traces   = (float*)(ws + o_small + 64);
    int*            ctrs     = (int*)(ws + o_small + 768);
    float*          cvals_raw= (float*)(ws + o_small + 832);
    unsigned int*   smallz   = (unsigned int*)(ws + o_small);
    int*            meta     = (int*)(ws + o_meta);
    int*            blk_cnt  = (int*)(ws + o_blkc);
    int*            blk_base = (int*)(ws + o_blkb);
    int*            order    = (int*)(ws + o_order);
    float*          part     = (float*)(ws + o_part);
    unsigned short* Xst      = (unsigned short*)(ws + o_xst);
    unsigned short* slab     = Xst;                  // E/G/H/K overlay Xst after cov

    hipLaunchKernelGGL(blkhist_kernel, dim3(256), dim3(256), 0, stream, Y, blk_cnt);
    hipLaunchKernelGGL(scan_kernel, dim3(1), dim3(1024), 0, stream, blk_cnt, meta, blk_base, smallz);
    hipLaunchKernelGGL(order_kernel, dim3(256), dim3(256), 0, stream, Y, blk_base, order);
    hipLaunchKernelGGL(gather_kernel, dim3(XP / 64), dim3(512), 0, stream, X, order, meta, Xst);
    hipLaunchKernelGGL(cov_mfma, dim3(3, NCLASS, SPL), dim3(256), 0, stream, Xst, meta, part);
    hipLaunchKernelGGL(merge_kernel, dim3(30, 8), dim3(256), 0, stream, part, cov, cvals_raw);
    hipLaunchKernelGGL(prep_kernel, dim3(11, 32), dim3(256), 0, stream, cov, meta, cvals_raw, slab);
    hipLaunchKernelGGL(power_kernel, dim3(220), dim3(256), 0, stream, slab, traces, cvals_raw, meta, out, ctrs);
}

// Round 8
// 174.717 us; speedup vs baseline: 2.1937x; 1.0944x over previous
//
#include <hip/hip_runtime.h>

#define N_ROWS 65536
#define N_COLS 256
#define NCLASS 10
#define XP 66176            // Xst col pitch: 65536 + 10*64 pad
#define SPL 8               // K-splits per (class,tile)
#define MSZ 65536           // 256*256 elements per matrix

typedef __attribute__((ext_vector_type(8))) short bf16x8;
typedef __attribute__((ext_vector_type(4))) float f32x4;

// meta layout (ints): [0..10] off_pad, [16..26] offsets (unpadded), [32..41] counts
// slab layout (bf16): s*11*MSZ + m*MSZ for s in {0:E, 1:G=E^2, 2:H=E^3, 3:K=E^4}
// small region (1024B): [64..767] traces, ints@768: [52] tr_ctr;
//   floats@832: cvals_raw[0..10] (diag sums)

static __device__ __forceinline__ unsigned short f2bf(float f) {
    unsigned int u = __float_as_uint(f);
    unsigned int r = (u + 0x7FFFu + ((u >> 16) & 1u)) >> 16;   // RTN-even
    return (unsigned short)r;
}
static __device__ __forceinline__ float bf2f(unsigned short s) {
    return __uint_as_float(((unsigned int)s) << 16);
}
static __device__ __forceinline__ void unpack8(const unsigned short* p, float* f) {
    uint4 u = *(const uint4*)p;
    f[0] = __uint_as_float(u.x << 16); f[1] = __uint_as_float(u.x & 0xffff0000u);
    f[2] = __uint_as_float(u.y << 16); f[3] = __uint_as_float(u.y & 0xffff0000u);
    f[4] = __uint_as_float(u.z << 16); f[5] = __uint_as_float(u.z & 0xffff0000u);
    f[6] = __uint_as_float(u.w << 16); f[7] = __uint_as_float(u.w & 0xffff0000u);
}
static __device__ __forceinline__ float scal_of(int b, const int* meta) {
    if (b < NCLASS) return (float)N_COLS / (((float)meta[32 + b] + 1e-8f) * 0.01f);
    return (float)N_COLS / ((float)N_ROWS * 0.01f);
}

// ---------------- Phase A: per-block class histogram (256 blocks) ----------------
__global__ __launch_bounds__(256) void blkhist_kernel(const int* __restrict__ Y,
                                                      int* __restrict__ blk_cnt) {
    __shared__ int h[NCLASS];
    int b = blockIdx.x, t = threadIdx.x;
    if (t < NCLASS) h[t] = 0;
    __syncthreads();
    atomicAdd(&h[Y[b * 256 + t]], 1);
    __syncthreads();
    if (t < NCLASS) blk_cnt[b * NCLASS + t] = h[t];
}

// ---------------- Phase B: scan (wave-per-class shuffle scans, 1 block) ----------------
// Also zeroes the small region (traces/ctrs/cvals_raw) so no separate memset dispatch.
__global__ __launch_bounds__(1024) void scan_kernel(const int* __restrict__ blk_cnt,
                                                    int* __restrict__ meta,
                                                    int* __restrict__ blk_base,
                                                    unsigned int* __restrict__ smallz) {
    int t = threadIdx.x;
    if (t < 256) smallz[t] = 0u;          // zero traces+ctr+cvals_raw (1024 B)
    int w = t >> 6, l = t & 63;
    __shared__ int tots[16];
    __shared__ int soff_s[16];
    int s0 = 0, s1 = 0, s2 = 0, s3 = 0;
    if (w < NCLASS) {
        s0 = blk_cnt[(l      ) * NCLASS + w];
        s1 = blk_cnt[(l +  64) * NCLASS + w];
        s2 = blk_cnt[(l + 128) * NCLASS + w];
        s3 = blk_cnt[(l + 192) * NCLASS + w];
    }
    int x0 = s0, x1 = s1, x2 = s2, x3 = s3;
    for (int d = 1; d < 64; d <<= 1) {
        int y0 = __shfl_up(x0, d, 64), y1 = __shfl_up(x1, d, 64);
        int y2 = __shfl_up(x2, d, 64), y3 = __shfl_up(x3, d, 64);
        if (l >= d) { x0 += y0; x1 += y1; x2 += y2; x3 += y3; }
    }
    int T0 = __shfl(x0, 63, 64), T1 = __shfl(x1, 63, 64);
    int T2 = __shfl(x2, 63, 64), T3 = __shfl(x3, 63, 64);
    if (w < NCLASS && l == 63) tots[w] = T0 + T1 + T2 + T3;
    __syncthreads();
    if (t == 0) {
        int off = 0, offp = 0;
        for (int c = 0; c < NCLASS; ++c) {
            soff_s[c] = off;
            meta[16 + c] = off;
            meta[c] = offp;
            meta[32 + c] = tots[c];
            off += tots[c];
            offp += (tots[c] + 63) & ~63;
        }
        meta[16 + NCLASS] = off;
        meta[NCLASS] = offp;
    }
    __syncthreads();
    if (w < NCLASS) {
        int base = soff_s[w];
        blk_base[(l      ) * NCLASS + w] = base + x0 - s0;
        blk_base[(l +  64) * NCLASS + w] = base + T0 + x1 - s1;
        blk_base[(l + 128) * NCLASS + w] = base + T0 + T1 + x2 - s2;
        blk_base[(l + 192) * NCLASS + w] = base + T0 + T1 + T2 + x3 - s3;
    }
}

// ---------------- Phase C: build sorted order (256 blocks) ----------------
__global__ __launch_bounds__(256) void order_kernel(const int* __restrict__ Y,
                                                    const int* __restrict__ blk_base,
                                                    int* __restrict__ order) {
    __shared__ int lcur[NCLASS];
    int b = blockIdx.x, t = threadIdx.x;
    if (t < NCLASS) lcur[t] = 0;
    __syncthreads();
    int i = b * 256 + t;
    int y = Y[i];
    int pos = blk_base[b * NCLASS + y] + atomicAdd(&lcur[y], 1);
    order[pos] = i;
}

// ---------------- gather + fp32->bf16 + transpose (rotation-swizzled LDS) ----------------
// 512 threads: 8 waves/block, 4 blocks/CU (LDS 32KB) -> 32 waves/CU resident.
__global__ __launch_bounds__(512) void gather_kernel(const float* __restrict__ X,
                                                     const int* __restrict__ order,
                                                     const int* __restrict__ meta,
                                                     unsigned short* __restrict__ Xst) {
    __shared__ unsigned int sT32[256 * 32];   // 32 KB
    int p0 = blockIdx.x * 64;
    if (p0 >= meta[NCLASS]) return;
    int cls = 0;
    while (p0 >= meta[cls + 1]) ++cls;       // 64-tiles never straddle classes
    int lp0 = p0 - meta[cls];
    int cnt = meta[32 + cls];
    int obase = meta[16 + cls];

    int t = threadIdx.x;
    int w = t >> 6, l = t & 63;

    #pragma unroll
    for (int rp = 0; rp < 4; ++rp) {
        int p2 = w * 4 + rp;                  // 0..31 (pos pair index)
        int lpa = lp0 + p2 * 2;
        int lpb = lpa + 1;
        int ra = (lpa < cnt) ? order[obase + lpa] : -1;   // wave-uniform
        int rb = (lpb < cnt) ? order[obase + lpb] : -1;
        float4 va = make_float4(0.f, 0.f, 0.f, 0.f);
        float4 vb = make_float4(0.f, 0.f, 0.f, 0.f);
        if (ra >= 0) va = *(const float4*)(X + (size_t)ra * N_COLS + l * 4);
        if (rb >= 0) vb = *(const float4*)(X + (size_t)rb * N_COLS + l * 4);
        unsigned int d0 = (unsigned)f2bf(va.x) | ((unsigned)f2bf(vb.x) << 16);
        unsigned int d1 = (unsigned)f2bf(va.y) | ((unsigned)f2bf(vb.y) << 16);
        unsigned int d2 = (unsigned)f2bf(va.z) | ((unsigned)f2bf(vb.z) << 16);
        unsigned int d3 = (unsigned)f2bf(va.w) | ((unsigned)f2bf(vb.w) << 16);
        int c0 = l * 4;
        sT32[(c0 + 0) * 32 + ((p2 + l + 0) & 31)] = d0;
        sT32[(c0 + 1) * 32 + ((p2 + l + 1) & 31)] = d1;
        sT32[(c0 + 2) * 32 + ((p2 + l + 2) & 31)] = d2;
        sT32[(c0 + 3) * 32 + ((p2 + l + 3) & 31)] = d3;
    }
    __syncthreads();

    int cb = t >> 3, pc = t & 7;              // cb 0..63
    #pragma unroll
    for (int j = 0; j < 4; ++j) {
        int col = cb + j * 64;
        int rot = (col >> 2) + (col & 3);
        const unsigned int* base = &sT32[col * 32];
        uint4 o;
        o.x = base[(pc * 4 + 0 + rot) & 31];
        o.y = base[(pc * 4 + 1 + rot) & 31];
        o.z = base[(pc * 4 + 2 + rot) & 31];
        o.w = base[(pc * 4 + 3 + rot) & 31];
        *(uint4*)(Xst + (size_t)col * XP + p0 + pc * 8) = o;
    }
}

// ---------------- cov via bf16 MFMA syrk -> per-split partial tiles ----------------
// Software-pipelined (R2-validated); diagonal tiles stage one LDS panel.
// SPL=8: each block amortizes its pipeline over ~13 chunks; part traffic halved.
__global__ __launch_bounds__(256) void cov_mfma(const unsigned short* __restrict__ Xst,
                                                const int* __restrict__ meta,
                                                float* __restrict__ part) {
    __shared__ unsigned short sA[128][72];
    __shared__ unsigned short sB[128][72];
    int cls = blockIdx.y;
    int tile = blockIdx.x;
    int ti = (tile == 2) ? 1 : 0;
    int tj = (tile == 0) ? 0 : 1;
    bool diag = (tile != 1);
    unsigned short (*SB)[72] = diag ? sA : sB;
    int kb = meta[cls];
    int len = meta[cls + 1] - kb;
    int nch = len >> 6;
    int s = blockIdx.z;
    int ch0 = (nch * s) / SPL, ch1 = (nch * (s + 1)) / SPL;

    int t = threadIdx.x;
    int lane = t & 63, wave = t >> 6;
    int wro = (wave >> 1) * 64, wco = (wave & 1) * 64;

    f32x4 acc[4][4] = {};
    int sr = t >> 1;
    int sq = (t & 1) * 32;

    uint4 a0, a1, a2, a3, b0, b1, b2, b3;
    if (ch0 < ch1) {
        int k0 = kb + ch0 * 64;
        const uint4* ga = (const uint4*)(Xst + (size_t)(ti * 128 + sr) * XP + k0 + sq);
        a0 = ga[0]; a1 = ga[1]; a2 = ga[2]; a3 = ga[3];
        if (!diag) {
            const uint4* gb = (const uint4*)(Xst + (size_t)(tj * 128 + sr) * XP + k0 + sq);
            b0 = gb[0]; b1 = gb[1]; b2 = gb[2]; b3 = gb[3];
        }
    }
    for (int ch = ch0; ch < ch1; ++ch) {
        __syncthreads();
        *(uint4*)&sA[sr][sq]      = a0;
        *(uint4*)&sA[sr][sq + 8]  = a1;
        *(uint4*)&sA[sr][sq + 16] = a2;
        *(uint4*)&sA[sr][sq + 24] = a3;
        if (!diag) {
            *(uint4*)&sB[sr][sq]      = b0;
            *(uint4*)&sB[sr][sq + 8]  = b1;
            *(uint4*)&sB[sr][sq + 16] = b2;
            *(uint4*)&sB[sr][sq + 24] = b3;
        }
        __syncthreads();
        if (ch + 1 < ch1) {
            int k0 = kb + (ch + 1) * 64;
            const uint4* ga = (const uint4*)(Xst + (size_t)(ti * 128 + sr) * XP + k0 + sq);
            a0 = ga[0]; a1 = ga[1]; a2 = ga[2]; a3 = ga[3];
            if (!diag) {
                const uint4* gb = (const uint4*)(Xst + (size_t)(tj * 128 + sr) * XP + k0 + sq);
                b0 = gb[0]; b1 = gb[1]; b2 = gb[2]; b3 = gb[3];
            }
        }
        #pragma unroll
        for (int ks = 0; ks < 64; ks += 32) {
            bf16x8 af[4], bfr[4];
            #pragma unroll
            for (int r = 0; r < 4; ++r)
                af[r] = *(const bf16x8*)&sA[wro + r * 16 + (lane & 15)][ks + (lane >> 4) * 8];
            #pragma unroll
            for (int c2 = 0; c2 < 4; ++c2)
                bfr[c2] = *(const bf16x8*)&SB[wco + c2 * 16 + (lane & 15)][ks + (lane >> 4) * 8];
            #pragma unroll
            for (int r = 0; r < 4; ++r) {
                #pragma unroll
                for (int c2 = 0; c2 < 4; ++c2)
                    acc[r][c2] = __builtin_amdgcn_mfma_f32_16x16x32_bf16(af[r], bfr[c2], acc[r][c2], 0, 0, 0);
            }
        }
    }

    float* po = part + (((size_t)s * NCLASS + cls) * 3 + tile) * 16384;
    int prl = wro + ((lane >> 4) << 2);
    int pcl = wco + (lane & 15);
    #pragma unroll
    for (int r = 0; r < 4; ++r) {
        #pragma unroll
        for (int c2 = 0; c2 < 4; ++c2) {
            #pragma unroll
            for (int v = 0; v < 4; ++v)
                po[(size_t)(prl + r * 16 + v) * 128 + pcl + c2 * 16] = acc[r][c2][v];
        }
    }
}

// ---------------- merge: sum SPL partials -> cov, + diagonal trace sums ----------------
// grid (30, 8). Diagonal values are in-register here, so the per-class trace
// (needed for c_b) is one block reduce + 2 atomics (R7-validated).
__global__ __launch_bounds__(256) void merge_kernel(const float* __restrict__ part,
                                                    float* __restrict__ cov,
                                                    float* __restrict__ cvals_raw) {
    __shared__ float red[256];
    int u = blockIdx.x;
    int cls = u / 3, tile = u % 3;
    int t = threadIdx.x;
    int lr = blockIdx.y * 16 + (t >> 4);   // local row 0..127
    int lc = (t & 15) * 8;                 // local col
    size_t off = (size_t)lr * 128 + lc;
    float4 s0 = make_float4(0.f, 0.f, 0.f, 0.f);
    float4 s1 = make_float4(0.f, 0.f, 0.f, 0.f);
    for (int s = 0; s < SPL; ++s) {
        const float* pb = part + (((size_t)s * NCLASS + cls) * 3 + tile) * 16384;
        float4 a = *(const float4*)(pb + off);
        float4 b = *(const float4*)(pb + off + 4);
        s0.x += a.x; s0.y += a.y; s0.z += a.z; s0.w += a.w;
        s1.x += b.x; s1.y += b.y; s1.z += b.z; s1.w += b.w;
    }
    int gr = (tile == 2 ? 128 : 0) + lr;
    int gc = (tile == 0 ? 0 : 128) + lc;
    float* cb = cov + (size_t)cls * MSZ + (size_t)gr * N_COLS + gc;
    *(float4*)cb = s0;
    *(float4*)(cb + 4) = s1;

    if (tile != 1) {                       // tiles (0,0) and (1,1) hold the diagonal
        float dval = 0.f;
        int j = lr - lc;
        if      (j == 0) dval = s0.x; else if (j == 1) dval = s0.y;
        else if (j == 2) dval = s0.z; else if (j == 3) dval = s0.w;
        else if (j == 4) dval = s1.x; else if (j == 5) dval = s1.y;
        else if (j == 6) dval = s1.z; else if (j == 7) dval = s1.w;
        red[t] = dval;
        __syncthreads();
        for (int st = 128; st > 0; st >>= 1) {
            if (t < st) red[t] += red[t + st];
            __syncthreads();
        }
        if (t == 0) {
            atomicAdd(&cvals_raw[cls], red[0]);
            atomicAdd(&cvals_raw[10], red[0]);
        }
    }
}

// ---------------- prep: E_b = M_b/c_b - I (bf16); grid (11, 32), pure streaming ----------------
__global__ __launch_bounds__(256) void prep_kernel(const float* __restrict__ cov,
                                                   const int* __restrict__ meta,
                                                   const float* __restrict__ cvals_raw,
                                                   unsigned short* __restrict__ slab) {
    int b = blockIdx.x;   // matrix 0..10
    int t = threadIdx.x;
    float scal = scal_of(b, meta);
    float raw = cvals_raw[b < NCLASS ? b : 10];
    float c = 1.f + scal * raw / 256.f;
    float es = scal / c;
    float dadd = 1.f / c - 1.f;

    int i  = blockIdx.y * 8 + (t >> 5);   // row
    int cg = (t & 31) * 8;                // col group (8 elems)
    bool mb = (i >> 7) > (cg >> 7);       // cov stores upper 128-blocks; mirror (1,0)
    float v[8];
    if (!mb) {
        size_t off = (size_t)i * N_COLS + cg;
        if (b < NCLASS) {
            float4 a = *(const float4*)(cov + (size_t)b * MSZ + off);
            float4 bq = *(const float4*)(cov + (size_t)b * MSZ + off + 4);
            v[0] = a.x; v[1] = a.y; v[2] = a.z; v[3] = a.w;
            v[4] = bq.x; v[5] = bq.y; v[6] = bq.z; v[7] = bq.w;
        } else {
            #pragma unroll
            for (int jj = 0; jj < 8; ++jj) v[jj] = 0.f;
            #pragma unroll
            for (int cl = 0; cl < NCLASS; ++cl) {
                float4 a = *(const float4*)(cov + (size_t)cl * MSZ + off);
                float4 bq = *(const float4*)(cov + (size_t)cl * MSZ + off + 4);
                v[0] += a.x; v[1] += a.y; v[2] += a.z; v[3] += a.w;
                v[4] += bq.x; v[5] += bq.y; v[6] += bq.z; v[7] += bq.w;
            }
        }
    } else {
        #pragma unroll
        for (int jj = 0; jj < 8; ++jj) {
            size_t off = (size_t)(cg + jj) * N_COLS + i;
            float s;
            if (b < NCLASS) s = cov[(size_t)b * MSZ + off];
            else {
                s = 0.f;
                #pragma unroll
                for (int cl = 0; cl < NCLASS; ++cl) s += cov[(size_t)cl * MSZ + off];
            }
            v[jj] = s;
        }
    }
    unsigned short o[8];
    #pragma unroll
    for (int jj = 0; jj < 8; ++jj)
        o[jj] = f2bf(es * v[jj] + ((cg + jj) == i ? dadd : 0.f));
    uint4 pk;
    pk.x = (unsigned)o[0] | ((unsigned)o[1] << 16);
    pk.y = (unsigned)o[2] | ((unsigned)o[3] << 16);
    pk.z = (unsigned)o[4] | ((unsigned)o[5] << 16);
    pk.w = (unsigned)o[6] | ((unsigned)o[7] << 16);
    *(uint4*)&slab[(size_t)b * MSZ + (size_t)i * N_COLS + cg] = pk;
}

// ---------------- mm_stage: D = A*B for symmetric bf16 256x256 (MFMA) ----------------
// Software-pipelined; diagonal syrk tiles stage one LDS panel. (R1/R2-validated)
__global__ __launch_bounds__(256) void mm_stage(unsigned short* __restrict__ slab,
                                                int ai0, int bi0, int di0,
                                                int ai1, int bi1, int di1) {
    int z = blockIdx.z;
    int ai = z ? ai1 : ai0, bi = z ? bi1 : bi0, di = z ? di1 : di0;
    int m = blockIdx.y;
    int tile = blockIdx.x;
    int ti = tile >> 1, tj = tile & 1;
    bool diag = (ai == bi) && (ti == tj);
    const unsigned short* A = slab + ((size_t)ai * 11 + m) * MSZ;
    const unsigned short* B = slab + ((size_t)bi * 11 + m) * MSZ;
    unsigned short* D = slab + ((size_t)di * 11 + m) * MSZ;

    __shared__ unsigned short sA[128][72];
    __shared__ unsigned short sB[128][72];
    unsigned short (*SB)[72] = diag ? sA : sB;
    int t = threadIdx.x;
    int lane = t & 63, wave = t >> 6;
    int wro = (wave >> 1) * 64, wco = (wave & 1) * 64;

    f32x4 acc[4][4] = {};
    int sr = t >> 1;
    int sq = (t & 1) * 32;

    uint4 a0, a1, a2, a3, b0, b1, b2, b3;
    {
        const uint4* ga = (const uint4*)(A + (size_t)(ti * 128 + sr) * N_COLS + sq);
        a0 = ga[0]; a1 = ga[1]; a2 = ga[2]; a3 = ga[3];
        if (!diag) {
            const uint4* gb = (const uint4*)(B + (size_t)(tj * 128 + sr) * N_COLS + sq);
            b0 = gb[0]; b1 = gb[1]; b2 = gb[2]; b3 = gb[3];
        }
    }
    for (int ch = 0; ch < 4; ++ch) {
        __syncthreads();
        *(uint4*)&sA[sr][sq]      = a0;
        *(uint4*)&sA[sr][sq + 8]  = a1;
        *(uint4*)&sA[sr][sq + 16] = a2;
        *(uint4*)&sA[sr][sq + 24] = a3;
        if (!diag) {
            *(uint4*)&sB[sr][sq]      = b0;
            *(uint4*)&sB[sr][sq + 8]  = b1;
            *(uint4*)&sB[sr][sq + 16] = b2;
            *(uint4*)&sB[sr][sq + 24] = b3;
        }
        __syncthreads();
        if (ch < 3) {
            int k0 = (ch + 1) * 64;
            const uint4* ga = (const uint4*)(A + (size_t)(ti * 128 + sr) * N_COLS + k0 + sq);
            a0 = ga[0]; a1 = ga[1]; a2 = ga[2]; a3 = ga[3];
            if (!diag) {
                const uint4* gb = (const uint4*)(B + (size_t)(tj * 128 + sr) * N_COLS + k0 + sq);
                b0 = gb[0]; b1 = gb[1]; b2 = gb[2]; b3 = gb[3];
            }
        }
        #pragma unroll
        for (int ks = 0; ks < 64; ks += 32) {
            bf16x8 af[4], bfr[4];
            #pragma unroll
            for (int r = 0; r < 4; ++r)
                af[r] = *(const bf16x8*)&sA[wro + r * 16 + (lane & 15)][ks + (lane >> 4) * 8];
            #pragma unroll
            for (int c2 = 0; c2 < 4; ++c2)
                bfr[c2] = *(const bf16x8*)&SB[wco + c2 * 16 + (lane & 15)][ks + (lane >> 4) * 8];
            #pragma unroll
            for (int r = 0; r < 4; ++r) {
                #pragma unroll
                for (int c2 = 0; c2 < 4; ++c2)
                    acc[r][c2] = __builtin_amdgcn_mfma_f32_16x16x32_bf16(af[r], bfr[c2], acc[r][c2], 0, 0, 0);
            }
        }
    }

    int prow = ti * 128 + wro + ((lane >> 4) << 2);
    int pcol = tj * 128 + wco + (lane & 15);
    #pragma unroll
    for (int r = 0; r < 4; ++r) {
        #pragma unroll
        for (int c2 = 0; c2 < 4; ++c2) {
            #pragma unroll
            for (int v = 0; v < 4; ++v)
                D[(size_t)(prow + r * 16 + v) * N_COLS + pcol + c2 * 16] = f2bf(acc[r][c2][v]);
        }
    }
}

// ---------------- trace + fused finalize (last-block counter, R2-validated) ----------------
// grid (11, 8). traces[m*16+v]: v=0:tr2 .. 6:tr8, 7:tr1.
__global__ __launch_bounds__(256) void trace_fin_kernel(const unsigned short* __restrict__ slab,
                                                        float* __restrict__ traces,
                                                        const float* __restrict__ cvals_raw,
                                                        const int* __restrict__ meta,
                                                        float* __restrict__ out,
                                                        unsigned int* __restrict__ ctr) {
    int m = blockIdx.x, t = threadIdx.x;
    int r  = blockIdx.y * 32 + (t >> 3);   // row
    int cs = (t & 7) * 32;                 // col segment (32 elems)
    const unsigned short* E = slab + (size_t)m * MSZ;
    const unsigned short* G = E + (size_t)11 * MSZ;
    const unsigned short* H = E + (size_t)22 * MSZ;
    const unsigned short* K = E + (size_t)33 * MSZ;

    float a0 = 0, a1 = 0, a2 = 0, a3 = 0, a4 = 0, a5 = 0, a6 = 0;
    float t1 = (r >= cs && r < cs + 32) ? bf2f(E[(size_t)r * 257]) : 0.f;
    size_t rb = (size_t)r * N_COLS + cs;
    #pragma unroll
    for (int cg = 0; cg < 32; cg += 8) {
        float e[8], g[8], h[8], k[8];
        unpack8(E + rb + cg, e);
        unpack8(G + rb + cg, g);
        unpack8(H + rb + cg, h);
        unpack8(K + rb + cg, k);
        #pragma unroll
        for (int j = 0; j < 8; ++j) {
            a0 = fmaf(e[j], e[j], a0);   // tr2
            a1 = fmaf(e[j], g[j], a1);   // tr3
            a2 = fmaf(g[j], g[j], a2);   // tr4
            a3 = fmaf(g[j], h[j], a3);   // tr5
            a4 = fmaf(h[j], h[j], a4);   // tr6
            a5 = fmaf(h[j], k[j], a5);   // tr7
            a6 = fmaf(k[j], k[j], a6);   // tr8
        }
    }
    float vals[8] = {a0, a1, a2, a3, a4, a5, a6, t1};
    #pragma unroll
    for (int v = 0; v < 8; ++v) {
        float x = vals[v];
        #pragma unroll
        for (int d = 32; d > 0; d >>= 1) x += __shfl_down(x, d, 64);
        if ((t & 63) == 0) atomicAdd(&traces[m * 16 + v], x);
    }

    // -------- fused finalize: last of the 88 blocks --------
    __threadfence();
    __syncthreads();
    if (t == 0) {
        unsigned int prev = atomicAdd(ctr, 1u);
        if (prev == 87u) {
            __threadfence();
            float logdet[11];
            for (int mm = 0; mm < 11; ++mm) {
                float tr[8];
                #pragma unroll
                for (int v = 0; v < 8; ++v)
                    tr[v] = __hip_atomic_load(&traces[mm * 16 + v],
                                              __ATOMIC_RELAXED, __HIP_MEMORY_SCOPE_AGENT);
                float raw = __hip_atomic_load((float*)&cvals_raw[mm < NCLASS ? mm : 10],
                                              __ATOMIC_RELAXED, __HIP_MEMORY_SCOPE_AGENT);
                float c = 1.f + scal_of(mm, meta) * raw / 256.f;
                logdet[mm] = 256.f * __logf(c)
                           + tr[7]
                           - tr[0] / 2.f + tr[1] / 3.f - tr[2] / 4.f + tr[3] / 5.f
                           - tr[4] / 6.f + tr[5] / 7.f - tr[6] / 8.f;
            }
            float discrimn = 0.5f * logdet[NCLASS];       // GAM1 == 1 => empi == theo
            float compress = 0.f;
            for (int k = 0; k < NCLASS; ++k) {
                float trp = (float)meta[32 + k] + 1e-8f;
                compress += logdet[k] * trp;
            }
            compress = compress / (float)N_ROWS * 0.5f;
            out[0] = -discrimn + compress;                // GAM2 == 1
            out[1] = discrimn;
            out[2] = compress;
            out[3] = discrimn;
            out[4] = compress;
        }
    }
}

extern "C" void kernel_launch(void* const* d_in, const int* in_sizes, int n_in,
                              void* d_out, int out_size, void* d_ws, size_t ws_size,
                              hipStream_t stream) {
    const float* X = (const float*)d_in[0];
    const int*   Y = (const int*)d_in[1];
    float* out = (float*)d_out;

    char* ws = (char*)d_ws;
    const size_t o_cov   = 0;                        // 10*256*256*4 = 2,621,440
    const size_t o_small = 2621440;                  // traces@64, ctr@976, cvals_raw@832
    const size_t o_meta  = o_small + 1024;           // 64 ints
    const size_t o_blkc  = o_meta + 256;             // 2560 ints
    const size_t o_blkb  = o_blkc + 10240;           // 2560 ints
    const size_t o_order = o_blkb + 10240;           // 65536 ints
    const size_t o_part  = o_order + 262144;         // 8*10*3*16384*4 = 15,728,640
    const size_t o_xst   = o_part + 15728640;        // 256*XP*2 = 33,882,112

    float*          cov      = (float*)(ws + o_cov);
    float*          traces   = (float*)(ws + o_small + 64);
    float*          cvals_raw= (float*)(ws + o_small + 832);
    unsigned int*   ctr      = (unsigned int*)(ws + o_small + 976);
    unsigned int*   smallz   = (unsigned int*)(ws + o_small);
    int*            meta     = (int*)(ws + o_meta);
    int*            blk_cnt  = (int*)(ws + o_blkc);
    int*            blk_base = (int*)(ws + o_blkb);
    int*            order    = (int*)(ws + o_order);
    float*          part     = (float*)(ws + o_part);
    unsigned short* Xst      = (unsigned short*)(ws + o_xst);
    unsigned short* slab     = Xst;                  // E/G/H/K overlay Xst after cov

    hipLaunchKernelGGL(blkhist_kernel, dim3(256), dim3(256), 0, stream, Y, blk_cnt);
    hipLaunchKernelGGL(scan_kernel, dim3(1), dim3(1024), 0, stream, blk_cnt, meta, blk_base, smallz);
    hipLaunchKernelGGL(order_kernel, dim3(256), dim3(256), 0, stream, Y, blk_base, order);
    hipLaunchKernelGGL(gather_kernel, dim3(XP / 64), dim3(512), 0, stream, X, order, meta, Xst);
    hipLaunchKernelGGL(cov_mfma, dim3(3, NCLASS, SPL), dim3(256), 0, stream, Xst, meta, part);
    hipLaunchKernelGGL(merge_kernel, dim3(30, 8), dim3(256), 0, stream, part, cov, cvals_raw);
    hipLaunchKernelGGL(prep_kernel, dim3(11, 32), dim3(256), 0, stream, cov, meta, cvals_raw, slab);
    // S1: G = E*E
    hipLaunchKernelGGL(mm_stage, dim3(4, 11, 1), dim3(256), 0, stream, slab, 0, 0, 1, 0, 0, 1);
    // S2: H = E*G ; K = G*G
    hipLaunchKernelGGL(mm_stage, dim3(4, 11, 2), dim3(256), 0, stream, slab, 0, 1, 2, 1, 1, 3);
    hipLaunchKernelGGL(trace_fin_kernel, dim3(11, 8), dim3(256), 0, stream,
                       slab, traces, cvals_raw, meta, out, ctr);
}

// Round 9
// 174.681 us; speedup vs baseline: 2.1941x; 1.0002x over previous
//
#include <hip/hip_runtime.h>

#define N_ROWS 65536
#define N_COLS 256
#define NCLASS 10
#define XP 66176            // Xst col pitch: 65536 + 10*64 pad
#define SPL 8               // K-splits per (class,tile)
#define MSZ 65536           // 256*256 elements per matrix

typedef __attribute__((ext_vector_type(8))) short bf16x8;
typedef __attribute__((ext_vector_type(4))) float f32x4;

// meta layout (ints): [0..10] off_pad, [16..26] offsets (unpadded), [32..41] counts
// slab layout (bf16): s*11*MSZ + m*MSZ for s in {0:E, 1:G=E^2, 2:H=E^3, 3:K=E^4}
// small region (1024B): [64..767] traces, ctr@976, cvals_raw@832

static __device__ __forceinline__ unsigned short f2bf(float f) {
    unsigned int u = __float_as_uint(f);
    unsigned int r = (u + 0x7FFFu + ((u >> 16) & 1u)) >> 16;   // RTN-even
    return (unsigned short)r;
}
static __device__ __forceinline__ float bf2f(unsigned short s) {
    return __uint_as_float(((unsigned int)s) << 16);
}
static __device__ __forceinline__ void unpack8(const unsigned short* p, float* f) {
    uint4 u = *(const uint4*)p;
    f[0] = __uint_as_float(u.x << 16); f[1] = __uint_as_float(u.x & 0xffff0000u);
    f[2] = __uint_as_float(u.y << 16); f[3] = __uint_as_float(u.y & 0xffff0000u);
    f[4] = __uint_as_float(u.z << 16); f[5] = __uint_as_float(u.z & 0xffff0000u);
    f[6] = __uint_as_float(u.w << 16); f[7] = __uint_as_float(u.w & 0xffff0000u);
}
static __device__ __forceinline__ float scal_of(int b, const int* meta) {
    if (b < NCLASS) return (float)N_COLS / (((float)meta[32 + b] + 1e-8f) * 0.01f);
    return (float)N_COLS / ((float)N_ROWS * 0.01f);
}
// async global->LDS, 16B per lane; LDS dest = wave-uniform base + lane*16
static __device__ __forceinline__ void gld_lds16(const unsigned short* g, unsigned short* l) {
    __builtin_amdgcn_global_load_lds(
        (const __attribute__((address_space(1))) unsigned int*)g,
        (__attribute__((address_space(3))) unsigned int*)l, 16, 0, 0);
}

// ---------------- Phase A: per-block class histogram (256 blocks) ----------------
__global__ __launch_bounds__(256) void blkhist_kernel(const int* __restrict__ Y,
                                                      int* __restrict__ blk_cnt) {
    __shared__ int h[NCLASS];
    int b = blockIdx.x, t = threadIdx.x;
    if (t < NCLASS) h[t] = 0;
    __syncthreads();
    atomicAdd(&h[Y[b * 256 + t]], 1);
    __syncthreads();
    if (t < NCLASS) blk_cnt[b * NCLASS + t] = h[t];
}

// ---------------- Phase B: scan (wave-per-class shuffle scans, 1 block) ----------------
__global__ __launch_bounds__(1024) void scan_kernel(const int* __restrict__ blk_cnt,
                                                    int* __restrict__ meta,
                                                    int* __restrict__ blk_base,
                                                    unsigned int* __restrict__ smallz) {
    int t = threadIdx.x;
    if (t < 256) smallz[t] = 0u;          // zero traces+ctr+cvals_raw (1024 B)
    int w = t >> 6, l = t & 63;
    __shared__ int tots[16];
    __shared__ int soff_s[16];
    int s0 = 0, s1 = 0, s2 = 0, s3 = 0;
    if (w < NCLASS) {
        s0 = blk_cnt[(l      ) * NCLASS + w];
        s1 = blk_cnt[(l +  64) * NCLASS + w];
        s2 = blk_cnt[(l + 128) * NCLASS + w];
        s3 = blk_cnt[(l + 192) * NCLASS + w];
    }
    int x0 = s0, x1 = s1, x2 = s2, x3 = s3;
    for (int d = 1; d < 64; d <<= 1) {
        int y0 = __shfl_up(x0, d, 64), y1 = __shfl_up(x1, d, 64);
        int y2 = __shfl_up(x2, d, 64), y3 = __shfl_up(x3, d, 64);
        if (l >= d) { x0 += y0; x1 += y1; x2 += y2; x3 += y3; }
    }
    int T0 = __shfl(x0, 63, 64), T1 = __shfl(x1, 63, 64);
    int T2 = __shfl(x2, 63, 64), T3 = __shfl(x3, 63, 64);
    if (w < NCLASS && l == 63) tots[w] = T0 + T1 + T2 + T3;
    __syncthreads();
    if (t == 0) {
        int off = 0, offp = 0;
        for (int c = 0; c < NCLASS; ++c) {
            soff_s[c] = off;
            meta[16 + c] = off;
            meta[c] = offp;
            meta[32 + c] = tots[c];
            off += tots[c];
            offp += (tots[c] + 63) & ~63;
        }
        meta[16 + NCLASS] = off;
        meta[NCLASS] = offp;
    }
    __syncthreads();
    if (w < NCLASS) {
        int base = soff_s[w];
        blk_base[(l      ) * NCLASS + w] = base + x0 - s0;
        blk_base[(l +  64) * NCLASS + w] = base + T0 + x1 - s1;
        blk_base[(l + 128) * NCLASS + w] = base + T0 + T1 + x2 - s2;
        blk_base[(l + 192) * NCLASS + w] = base + T0 + T1 + T2 + x3 - s3;
    }
}

// ---------------- Phase C: build sorted order (256 blocks) ----------------
__global__ __launch_bounds__(256) void order_kernel(const int* __restrict__ Y,
                                                    const int* __restrict__ blk_base,
                                                    int* __restrict__ order) {
    __shared__ int lcur[NCLASS];
    int b = blockIdx.x, t = threadIdx.x;
    if (t < NCLASS) lcur[t] = 0;
    __syncthreads();
    int i = b * 256 + t;
    int y = Y[i];
    int pos = blk_base[b * NCLASS + y] + atomicAdd(&lcur[y], 1);
    order[pos] = i;
}

// ---------------- gather + fp32->bf16 + transpose (rotation-swizzled LDS) ----------------
__global__ __launch_bounds__(512) void gather_kernel(const float* __restrict__ X,
                                                     const int* __restrict__ order,
                                                     const int* __restrict__ meta,
                                                     unsigned short* __restrict__ Xst) {
    __shared__ unsigned int sT32[256 * 32];   // 32 KB
    int p0 = blockIdx.x * 64;
    if (p0 >= meta[NCLASS]) return;
    int cls = 0;
    while (p0 >= meta[cls + 1]) ++cls;       // 64-tiles never straddle classes
    int lp0 = p0 - meta[cls];
    int cnt = meta[32 + cls];
    int obase = meta[16 + cls];

    int t = threadIdx.x;
    int w = t >> 6, l = t & 63;

    #pragma unroll
    for (int rp = 0; rp < 4; ++rp) {
        int p2 = w * 4 + rp;                  // 0..31 (pos pair index)
        int lpa = lp0 + p2 * 2;
        int lpb = lpa + 1;
        int ra = (lpa < cnt) ? order[obase + lpa] : -1;   // wave-uniform
        int rb = (lpb < cnt) ? order[obase + lpb] : -1;
        float4 va = make_float4(0.f, 0.f, 0.f, 0.f);
        float4 vb = make_float4(0.f, 0.f, 0.f, 0.f);
        if (ra >= 0) va = *(const float4*)(X + (size_t)ra * N_COLS + l * 4);
        if (rb >= 0) vb = *(const float4*)(X + (size_t)rb * N_COLS + l * 4);
        unsigned int d0 = (unsigned)f2bf(va.x) | ((unsigned)f2bf(vb.x) << 16);
        unsigned int d1 = (unsigned)f2bf(va.y) | ((unsigned)f2bf(vb.y) << 16);
        unsigned int d2 = (unsigned)f2bf(va.z) | ((unsigned)f2bf(vb.z) << 16);
        unsigned int d3 = (unsigned)f2bf(va.w) | ((unsigned)f2bf(vb.w) << 16);
        int c0 = l * 4;
        sT32[(c0 + 0) * 32 + ((p2 + l + 0) & 31)] = d0;
        sT32[(c0 + 1) * 32 + ((p2 + l + 1) & 31)] = d1;
        sT32[(c0 + 2) * 32 + ((p2 + l + 2) & 31)] = d2;
        sT32[(c0 + 3) * 32 + ((p2 + l + 3) & 31)] = d3;
    }
    __syncthreads();

    int cb = t >> 3, pc = t & 7;              // cb 0..63
    #pragma unroll
    for (int j = 0; j < 4; ++j) {
        int col = cb + j * 64;
        int rot = (col >> 2) + (col & 3);
        const unsigned int* base = &sT32[col * 32];
        uint4 o;
        o.x = base[(pc * 4 + 0 + rot) & 31];
        o.y = base[(pc * 4 + 1 + rot) & 31];
        o.z = base[(pc * 4 + 2 + rot) & 31];
        o.w = base[(pc * 4 + 3 + rot) & 31];
        *(uint4*)(Xst + (size_t)col * XP + p0 + pc * 8) = o;
    }
}

// ---------------- cov via bf16 MFMA syrk, global_load_lds double-buffered ----------------
// Linear [128][64] LDS per panel per buffer; XOR-swizzle both sides:
// write: lane l covers row r (r&7 == l>>3), source col-unit (l&7)^(l>>3) -> LDS unit l&7
// read:  fragment unit q=(ks>>3)+(lane>>4) of row f lives at LDS unit q^(f&7)
__global__ __launch_bounds__(256) void cov_mfma(const unsigned short* __restrict__ Xst,
                                                const int* __restrict__ meta,
                                                float* __restrict__ part) {
    __shared__ unsigned short sAl[2][128 * 64];   // 32 KB
    __shared__ unsigned short sBl[2][128 * 64];   // 32 KB
    int cls = blockIdx.y;
    int tile = blockIdx.x;
    int ti = (tile == 2) ? 1 : 0;
    int tj = (tile == 0) ? 0 : 1;
    bool diag = (tile != 1);
    int kb = meta[cls];
    int len = meta[cls + 1] - kb;
    int nch = len >> 6;
    int s = blockIdx.z;
    int ch0 = (nch * s) / SPL, ch1 = (nch * (s + 1)) / SPL;

    int t = threadIdx.x;
    int lane = t & 63, wave = t >> 6;
    int wro = (wave >> 1) * 64, wco = (wave & 1) * 64;
    int w32 = wave * 32;
    int rsub = lane >> 3;                              // 0..7
    int swz = (((lane & 7) ^ rsub) << 3);              // pre-swizzled source col (shorts)

    f32x4 acc[4][4] = {};
    int cur = 0;

    if (ch0 < ch1) {                                   // prologue: stage chunk ch0 -> buf 0
        int k0 = kb + ch0 * 64;
        #pragma unroll
        for (int i = 0; i < 4; ++i) {
            int rr = w32 + i * 8 + rsub;
            gld_lds16(Xst + (size_t)(ti * 128 + rr) * XP + k0 + swz,
                      &sAl[0][(w32 + i * 8) * 64]);
        }
        if (!diag) {
            #pragma unroll
            for (int i = 0; i < 4; ++i) {
                int rr = w32 + i * 8 + rsub;
                gld_lds16(Xst + (size_t)(tj * 128 + rr) * XP + k0 + swz,
                          &sBl[0][(w32 + i * 8) * 64]);
            }
        }
    }

    for (int ch = ch0; ch < ch1; ++ch) {
        __syncthreads();                               // drains vmcnt -> buf[cur] ready
        if (ch + 1 < ch1) {                            // stage next chunk -> buf[cur^1]
            int k0 = kb + (ch + 1) * 64;
            #pragma unroll
            for (int i = 0; i < 4; ++i) {
                int rr = w32 + i * 8 + rsub;
                gld_lds16(Xst + (size_t)(ti * 128 + rr) * XP + k0 + swz,
                          &sAl[cur ^ 1][(w32 + i * 8) * 64]);
            }
            if (!diag) {
                #pragma unroll
                for (int i = 0; i < 4; ++i) {
                    int rr = w32 + i * 8 + rsub;
                    gld_lds16(Xst + (size_t)(tj * 128 + rr) * XP + k0 + swz,
                              &sBl[cur ^ 1][(w32 + i * 8) * 64]);
                }
            }
        }
        const unsigned short* Ab = sAl[cur];
        const unsigned short* Bb = diag ? sAl[cur] : sBl[cur];
        #pragma unroll
        for (int ks = 0; ks < 64; ks += 32) {
            int q = (ks >> 3) + (lane >> 4);
            bf16x8 af[4], bfr[4];
            #pragma unroll
            for (int r = 0; r < 4; ++r) {
                int f = wro + r * 16 + (lane & 15);
                af[r] = *(const bf16x8*)&Ab[f * 64 + ((q ^ (f & 7)) << 3)];
            }
            #pragma unroll
            for (int c2 = 0; c2 < 4; ++c2) {
                int f = wco + c2 * 16 + (lane & 15);
                bfr[c2] = *(const bf16x8*)&Bb[f * 64 + ((q ^ (f & 7)) << 3)];
            }
            #pragma unroll
            for (int r = 0; r < 4; ++r) {
                #pragma unroll
                for (int c2 = 0; c2 < 4; ++c2)
                    acc[r][c2] = __builtin_amdgcn_mfma_f32_16x16x32_bf16(af[r], bfr[c2], acc[r][c2], 0, 0, 0);
            }
        }
        cur ^= 1;
    }

    float* po = part + (((size_t)s * NCLASS + cls) * 3 + tile) * 16384;
    int prl = wro + ((lane >> 4) << 2);
    int pcl = wco + (lane & 15);
    #pragma unroll
    for (int r = 0; r < 4; ++r) {
        #pragma unroll
        for (int c2 = 0; c2 < 4; ++c2) {
            #pragma unroll
            for (int v = 0; v < 4; ++v)
                po[(size_t)(prl + r * 16 + v) * 128 + pcl + c2 * 16] = acc[r][c2][v];
        }
    }
}

// ---------------- merge: sum SPL partials -> cov, + diagonal trace sums ----------------
__global__ __launch_bounds__(256) void merge_kernel(const float* __restrict__ part,
                                                    float* __restrict__ cov,
                                                    float* __restrict__ cvals_raw) {
    __shared__ float red[256];
    int u = blockIdx.x;
    int cls = u / 3, tile = u % 3;
    int t = threadIdx.x;
    int lr = blockIdx.y * 16 + (t >> 4);   // local row 0..127
    int lc = (t & 15) * 8;                 // local col
    size_t off = (size_t)lr * 128 + lc;
    float4 s0 = make_float4(0.f, 0.f, 0.f, 0.f);
    float4 s1 = make_float4(0.f, 0.f, 0.f, 0.f);
    for (int s = 0; s < SPL; ++s) {
        const float* pb = part + (((size_t)s * NCLASS + cls) * 3 + tile) * 16384;
        float4 a = *(const float4*)(pb + off);
        float4 b = *(const float4*)(pb + off + 4);
        s0.x += a.x; s0.y += a.y; s0.z += a.z; s0.w += a.w;
        s1.x += b.x; s1.y += b.y; s1.z += b.z; s1.w += b.w;
    }
    int gr = (tile == 2 ? 128 : 0) + lr;
    int gc = (tile == 0 ? 0 : 128) + lc;
    float* cb = cov + (size_t)cls * MSZ + (size_t)gr * N_COLS + gc;
    *(float4*)cb = s0;
    *(float4*)(cb + 4) = s1;

    if (tile != 1) {                       // tiles (0,0) and (1,1) hold the diagonal
        float dval = 0.f;
        int j = lr - lc;
        if      (j == 0) dval = s0.x; else if (j == 1) dval = s0.y;
        else if (j == 2) dval = s0.z; else if (j == 3) dval = s0.w;
        else if (j == 4) dval = s1.x; else if (j == 5) dval = s1.y;
        else if (j == 6) dval = s1.z; else if (j == 7) dval = s1.w;
        red[t] = dval;
        __syncthreads();
        for (int st = 128; st > 0; st >>= 1) {
            if (t < st) red[t] += red[t + st];
            __syncthreads();
        }
        if (t == 0) {
            atomicAdd(&cvals_raw[cls], red[0]);
            atomicAdd(&cvals_raw[10], red[0]);
        }
    }
}

// ---------------- prep: E_b = M_b/c_b - I (bf16); grid (11, 32), pure streaming ----------------
__global__ __launch_bounds__(256) void prep_kernel(const float* __restrict__ cov,
                                                   const int* __restrict__ meta,
                                                   const float* __restrict__ cvals_raw,
                                                   unsigned short* __restrict__ slab) {
    int b = blockIdx.x;   // matrix 0..10
    int t = threadIdx.x;
    float scal = scal_of(b, meta);
    float raw = cvals_raw[b < NCLASS ? b : 10];
    float c = 1.f + scal * raw / 256.f;
    float es = scal / c;
    float dadd = 1.f / c - 1.f;

    int i  = blockIdx.y * 8 + (t >> 5);   // row
    int cg = (t & 31) * 8;                // col group (8 elems)
    bool mb = (i >> 7) > (cg >> 7);       // cov stores upper 128-blocks; mirror (1,0)
    float v[8];
    if (!mb) {
        size_t off = (size_t)i * N_COLS + cg;
        if (b < NCLASS) {
            float4 a = *(const float4*)(cov + (size_t)b * MSZ + off);
            float4 bq = *(const float4*)(cov + (size_t)b * MSZ + off + 4);
            v[0] = a.x; v[1] = a.y; v[2] = a.z; v[3] = a.w;
            v[4] = bq.x; v[5] = bq.y; v[6] = bq.z; v[7] = bq.w;
        } else {
            #pragma unroll
            for (int jj = 0; jj < 8; ++jj) v[jj] = 0.f;
            #pragma unroll
            for (int cl = 0; cl < NCLASS; ++cl) {
                float4 a = *(const float4*)(cov + (size_t)cl * MSZ + off);
                float4 bq = *(const float4*)(cov + (size_t)cl * MSZ + off + 4);
                v[0] += a.x; v[1] += a.y; v[2] += a.z; v[3] += a.w;
                v[4] += bq.x; v[5] += bq.y; v[6] += bq.z; v[7] += bq.w;
            }
        }
    } else {
        #pragma unroll
        for (int jj = 0; jj < 8; ++jj) {
            size_t off = (size_t)(cg + jj) * N_COLS + i;
            float s;
            if (b < NCLASS) s = cov[(size_t)b * MSZ + off];
            else {
                s = 0.f;
                #pragma unroll
                for (int cl = 0; cl < NCLASS; ++cl) s += cov[(size_t)cl * MSZ + off];
            }
            v[jj] = s;
        }
    }
    unsigned short o[8];
    #pragma unroll
    for (int jj = 0; jj < 8; ++jj)
        o[jj] = f2bf(es * v[jj] + ((cg + jj) == i ? dadd : 0.f));
    uint4 pk;
    pk.x = (unsigned)o[0] | ((unsigned)o[1] << 16);
    pk.y = (unsigned)o[2] | ((unsigned)o[3] << 16);
    pk.z = (unsigned)o[4] | ((unsigned)o[5] << 16);
    pk.w = (unsigned)o[6] | ((unsigned)o[7] << 16);
    *(uint4*)&slab[(size_t)b * MSZ + (size_t)i * N_COLS + cg] = pk;
}

// ---------------- mm_stage: D = A*B (bf16 256x256), global_load_lds double-buffered ----------------
__global__ __launch_bounds__(256) void mm_stage(unsigned short* __restrict__ slab,
                                                int ai0, int bi0, int di0,
                                                int ai1, int bi1, int di1) {
    __shared__ unsigned short sAl[2][128 * 64];
    __shared__ unsigned short sBl[2][128 * 64];
    int z = blockIdx.z;
    int ai = z ? ai1 : ai0, bi = z ? bi1 : bi0, di = z ? di1 : di0;
    int m = blockIdx.y;
    int tile = blockIdx.x;
    int ti = tile >> 1, tj = tile & 1;
    bool diag = (ai == bi) && (ti == tj);
    const unsigned short* A = slab + ((size_t)ai * 11 + m) * MSZ;
    const unsigned short* B = slab + ((size_t)bi * 11 + m) * MSZ;
    unsigned short* D = slab + ((size_t)di * 11 + m) * MSZ;

    int t = threadIdx.x;
    int lane = t & 63, wave = t >> 6;
    int wro = (wave >> 1) * 64, wco = (wave & 1) * 64;
    int w32 = wave * 32;
    int rsub = lane >> 3;
    int swz = (((lane & 7) ^ rsub) << 3);

    f32x4 acc[4][4] = {};
    int cur = 0;

    {   // prologue: stage chunk 0 -> buf 0
        #pragma unroll
        for (int i = 0; i < 4; ++i) {
            int rr = w32 + i * 8 + rsub;
            gld_lds16(A + (size_t)(ti * 128 + rr) * N_COLS + swz,
                      &sAl[0][(w32 + i * 8) * 64]);
        }
        if (!diag) {
            #pragma unroll
            for (int i = 0; i < 4; ++i) {
                int rr = w32 + i * 8 + rsub;
                gld_lds16(B + (size_t)(tj * 128 + rr) * N_COLS + swz,
                          &sBl[0][(w32 + i * 8) * 64]);
            }
        }
    }

    for (int ch = 0; ch < 4; ++ch) {
        __syncthreads();                               // drains vmcnt -> buf[cur] ready
        if (ch < 3) {
            int k0 = (ch + 1) * 64;
            #pragma unroll
            for (int i = 0; i < 4; ++i) {
                int rr = w32 + i * 8 + rsub;
                gld_lds16(A + (size_t)(ti * 128 + rr) * N_COLS + k0 + swz,
                          &sAl[cur ^ 1][(w32 + i * 8) * 64]);
            }
            if (!diag) {
                #pragma unroll
                for (int i = 0; i < 4; ++i) {
                    int rr = w32 + i * 8 + rsub;
                    gld_lds16(B + (size_t)(tj * 128 + rr) * N_COLS + k0 + swz,
                              &sBl[cur ^ 1][(w32 + i * 8) * 64]);
                }
            }
        }
        const unsigned short* Ab = sAl[cur];
        const unsigned short* Bb = diag ? sAl[cur] : sBl[cur];
        #pragma unroll
        for (int ks = 0; ks < 64; ks += 32) {
            int q = (ks >> 3) + (lane >> 4);
            bf16x8 af[4], bfr[4];
            #pragma unroll
            for (int r = 0; r < 4; ++r) {
                int f = wro + r * 16 + (lane & 15);
                af[r] = *(const bf16x8*)&Ab[f * 64 + ((q ^ (f & 7)) << 3)];
            }
            #pragma unroll
            for (int c2 = 0; c2 < 4; ++c2) {
                int f = wco + c2 * 16 + (lane & 15);
                bfr[c2] = *(const bf16x8*)&Bb[f * 64 + ((q ^ (f & 7)) << 3)];
            }
            #pragma unroll
            for (int r = 0; r < 4; ++r) {
                #pragma unroll
                for (int c2 = 0; c2 < 4; ++c2)
                    acc[r][c2] = __builtin_amdgcn_mfma_f32_16x16x32_bf16(af[r], bfr[c2], acc[r][c2], 0, 0, 0);
            }
        }
        cur ^= 1;
    }

    int prow = ti * 128 + wro + ((lane >> 4) << 2);
    int pcol = tj * 128 + wco + (lane & 15);
    #pragma unroll
    for (int r = 0; r < 4; ++r) {
        #pragma unroll
        for (int c2 = 0; c2 < 4; ++c2) {
            #pragma unroll
            for (int v = 0; v < 4; ++v)
                D[(size_t)(prow + r * 16 + v) * N_COLS + pcol + c2 * 16] = f2bf(acc[r][c2][v]);
        }
    }
}

// ---------------- trace + fused finalize (last-block counter) ----------------
__global__ __launch_bounds__(256) void trace_fin_kernel(const unsigned short* __restrict__ slab,
                                                        float* __restrict__ traces,
                                                        const float* __restrict__ cvals_raw,
                                                        const int* __restrict__ meta,
                                                        float* __restrict__ out,
                                                        unsigned int* __restrict__ ctr) {
    int m = blockIdx.x, t = threadIdx.x;
    int r  = blockIdx.y * 32 + (t >> 3);   // row
    int cs = (t & 7) * 32;                 // col segment (32 elems)
    const unsigned short* E = slab + (size_t)m * MSZ;
    const unsigned short* G = E + (size_t)11 * MSZ;
    const unsigned short* H = E + (size_t)22 * MSZ;
    const unsigned short* K = E + (size_t)33 * MSZ;

    float a0 = 0, a1 = 0, a2 = 0, a3 = 0, a4 = 0, a5 = 0, a6 = 0;
    float t1 = (r >= cs && r < cs + 32) ? bf2f(E[(size_t)r * 257]) : 0.f;
    size_t rb = (size_t)r * N_COLS + cs;
    #pragma unroll
    for (int cg = 0; cg < 32; cg += 8) {
        float e[8], g[8], h[8], k[8];
        unpack8(E + rb + cg, e);
        unpack8(G + rb + cg, g);
        unpack8(H + rb + cg, h);
        unpack8(K + rb + cg, k);
        #pragma unroll
        for (int j = 0; j < 8; ++j) {
            a0 = fmaf(e[j], e[j], a0);   // tr2
            a1 = fmaf(e[j], g[j], a1);   // tr3
            a2 = fmaf(g[j], g[j], a2);   // tr4
            a3 = fmaf(g[j], h[j], a3);   // tr5
            a4 = fmaf(h[j], h[j], a4);   // tr6
            a5 = fmaf(h[j], k[j], a5);   // tr7
            a6 = fmaf(k[j], k[j], a6);   // tr8
        }
    }
    float vals[8] = {a0, a1, a2, a3, a4, a5, a6, t1};
    #pragma unroll
    for (int v = 0; v < 8; ++v) {
        float x = vals[v];
        #pragma unroll
        for (int d = 32; d > 0; d >>= 1) x += __shfl_down(x, d, 64);
        if ((t & 63) == 0) atomicAdd(&traces[m * 16 + v], x);
    }

    // -------- fused finalize: last of the 88 blocks --------
    __threadfence();
    __syncthreads();
    if (t == 0) {
        unsigned int prev = atomicAdd(ctr, 1u);
        if (prev == 87u) {
            __threadfence();
            float logdet[11];
            for (int mm = 0; mm < 11; ++mm) {
                float tr[8];
                #pragma unroll
                for (int v = 0; v < 8; ++v)
                    tr[v] = __hip_atomic_load(&traces[mm * 16 + v],
                                              __ATOMIC_RELAXED, __HIP_MEMORY_SCOPE_AGENT);
                float raw = __hip_atomic_load((float*)&cvals_raw[mm < NCLASS ? mm : 10],
                                              __ATOMIC_RELAXED, __HIP_MEMORY_SCOPE_AGENT);
                float c = 1.f + scal_of(mm, meta) * raw / 256.f;
                logdet[mm] = 256.f * __logf(c)
                           + tr[7]
                           - tr[0] / 2.f + tr[1] / 3.f - tr[2] / 4.f + tr[3] / 5.f
                           - tr[4] / 6.f + tr[5] / 7.f - tr[6] / 8.f;
            }
            float discrimn = 0.5f * logdet[NCLASS];       // GAM1 == 1 => empi == theo
            float compress = 0.f;
            for (int k = 0; k < NCLASS; ++k) {
                float trp = (float)meta[32 + k] + 1e-8f;
                compress += logdet[k] * trp;
            }
            compress = compress / (float)N_ROWS * 0.5f;
            out[0] = -discrimn + compress;                // GAM2 == 1
            out[1] = discrimn;
            out[2] = compress;
            out[3] = discrimn;
            out[4] = compress;
        }
    }
}

extern "C" void kernel_launch(void* const* d_in, const int* in_sizes, int n_in,
                              void* d_out, int out_size, void* d_ws, size_t ws_size,
                              hipStream_t stream) {
    const float* X = (const float*)d_in[0];
    const int*   Y = (const int*)d_in[1];
    float* out = (float*)d_out;

    char* ws = (char*)d_ws;
    const size_t o_cov   = 0;                        // 10*256*256*4 = 2,621,440
    const size_t o_small = 2621440;                  // traces@64, cvals_raw@832, ctr@976
    const size_t o_meta  = o_small + 1024;           // 64 ints
    const size_t o_blkc  = o_meta + 256;             // 2560 ints
    const size_t o_blkb  = o_blkc + 10240;           // 2560 ints
    const size_t o_order = o_blkb + 10240;           // 65536 ints
    const size_t o_part  = o_order + 262144;         // 8*10*3*16384*4 = 15,728,640
    const size_t o_xst   = o_part + 15728640;        // 256*XP*2 = 33,882,112

    float*          cov      = (float*)(ws + o_cov);
    float*          traces   = (float*)(ws + o_small + 64);
    float*          cvals_raw= (float*)(ws + o_small + 832);
    unsigned int*   ctr      = (unsigned int*)(ws + o_small + 976);
    unsigned int*   smallz   = (unsigned int*)(ws + o_small);
    int*            meta     = (int*)(ws + o_meta);
    int*            blk_cnt  = (int*)(ws + o_blkc);
    int*            blk_base = (int*)(ws + o_blkb);
    int*            order    = (int*)(ws + o_order);
    float*          part     = (float*)(ws + o_part);
    unsigned short* Xst      = (unsigned short*)(ws + o_xst);
    unsigned short* slab     = Xst;                  // E/G/H/K overlay Xst after cov

    hipLaunchKernelGGL(blkhist_kernel, dim3(256), dim3(256), 0, stream, Y, blk_cnt);
    hipLaunchKernelGGL(scan_kernel, dim3(1), dim3(1024), 0, stream, blk_cnt, meta, blk_base, smallz);
    hipLaunchKernelGGL(order_kernel, dim3(256), dim3(256), 0, stream, Y, blk_base, order);
    hipLaunchKernelGGL(gather_kernel, dim3(XP / 64), dim3(512), 0, stream, X, order, meta, Xst);
    hipLaunchKernelGGL(cov_mfma, dim3(3, NCLASS, SPL), dim3(256), 0, stream, Xst, meta, part);
    hipLaunchKernelGGL(merge_kernel, dim3(30, 8), dim3(256), 0, stream, part, cov, cvals_raw);
    hipLaunchKernelGGL(prep_kernel, dim3(11, 32), dim3(256), 0, stream, cov, meta, cvals_raw, slab);
    // S1: G = E*E
    hipLaunchKernelGGL(mm_stage, dim3(4, 11, 1), dim3(256), 0, stream, slab, 0, 0, 1, 0, 0, 1);
    // S2: H = E*G ; K = G*G
    hipLaunchKernelGGL(mm_stage, dim3(4, 11, 2), dim3(256), 0, stream, slab, 0, 1, 2, 1, 1, 3);
    hipLaunchKernelGGL(trace_fin_kernel, dim3(11, 8), dim3(256), 0, stream,
                       slab, traces, cvals_raw, meta, out, ctr);
}